// Round 16
// baseline (1377.515 us; speedup 1.0000x reference)
//
#include <hip/hip_runtime.h>

#define DEV __device__ __forceinline__

typedef __attribute__((ext_vector_type(8))) short short8;
typedef __attribute__((ext_vector_type(4))) float f32x4;
typedef unsigned short u16;

constexpr int kV = 80000, kD = 300, kNN = 32, kEE = 64, kHH = 4, kCC = 75;
constexpr int kB = 32, kT = 35, kU = 1024, kVG = 50000;
constexpr int kG = kB * kT;          // 1120
constexpr int kM = kG;

constexpr size_t alignup(size_t x) { return (x + 255) & ~size_t(255); }
constexpr size_t OFF_BAR   = 0;       // F0/F1/F2: 3 x 256 flags (4 KB reserved)
constexpr size_t OFF_WSRC  = 4096;
constexpr size_t OFF_WDST  = alignup(OFF_WSRC + 1200 * 4);
constexpr size_t OFF_BIAS  = alignup(OFF_WDST + 1200 * 4);
constexpr size_t OFF_SIG   = alignup(OFF_BIAS + 3 * 4096 * 4);
constexpr size_t OFF_WX0   = alignup(OFF_SIG + (size_t)35 * 32 * 640 * 2);
constexpr size_t OFF_WX12  = alignup(OFF_WX0 + (size_t)4096 * 640 * 2);
constexpr size_t OFF_GATES = alignup(OFF_WX12 + (size_t)2 * 4096 * 1024 * 2);
constexpr size_t OFF_HIST  = alignup(OFF_GATES + (size_t)1120 * 4096 * 4);
constexpr size_t OFF_PART  = alignup(OFF_HIST + (size_t)3 * 35 * 32 * 1024 * 2);
constexpr size_t OFF_LSE   = alignup(OFF_PART + (size_t)1120 * 784 * 8);
constexpr size_t OFF_LINWB = alignup(OFF_LSE + 1120 * 4);
constexpr size_t kLinWBytes = (size_t)kVG * 1024 * 2;
constexpr size_t kNeedBW   = OFF_LINWB + kLinWBytes;

DEV u16 f2bf(float f) {
  union { float f; unsigned u; } v; v.f = f;
  unsigned r = v.u + 0x7fffu + ((v.u >> 16) & 1u);
  return (u16)(r >> 16);
}
DEV float fexp(float x) { return __builtin_amdgcn_exp2f(x * 1.4426950408889634f); }
DEV float fsigm(float x) {
  float t = __builtin_amdgcn_exp2f(-1.4426950408889634f * x);
  return __builtin_amdgcn_rcpf(1.f + t);
}
DEV float ftanh(float x) {
  float xc = fminf(fmaxf(x, -20.f), 20.f);
  float t = __builtin_amdgcn_exp2f(2.8853900817779268f * xc);
  return (t - 1.f) * __builtin_amdgcn_rcpf(t + 1.f);
}
DEV f32x4 mfma16(short8 a, short8 b, f32x4 c) {
  return __builtin_amdgcn_mfma_f32_16x16x32_bf16(a, b, c, 0, 0, 0);
}
// store a bf16 directly to the coherent LLC (bypass non-coherent per-XCD L2).
DEV void store_u16_llc(u16* p, u16 v) {
  unsigned vv = v;
  asm volatile("global_store_short %0, %1, off sc0 sc1"
               :: "v"(p), "v"(vv) : "memory");
}
// async global->LDS DMA, 16B/lane
DEV void gll16(const void* g, void* l) {
  __builtin_amdgcn_global_load_lds(
      (const __attribute__((address_space(1))) unsigned int*)g,
      (__attribute__((address_space(3))) unsigned int*)l, 16, 0, 0);
}
// load 8 fp32, convert to bf16 short8
DEV short8 ld8bf(const float* p) {
  float4 a = *(const float4*)p;
  float4 b = *(const float4*)(p + 4);
  u16 t[8] = {f2bf(a.x), f2bf(a.y), f2bf(a.z), f2bf(a.w),
              f2bf(b.x), f2bf(b.y), f2bf(b.z), f2bf(b.w)};
  return *(const short8*)t;
}
// wave-level wait: all 256 entries of F >= tgt  (4 coalesced polls/lane)
DEV void wait256(const unsigned* F, unsigned tgt, int lane) {
  while (true) {
    int ok = (__hip_atomic_load(F + lane, __ATOMIC_RELAXED, __HIP_MEMORY_SCOPE_AGENT) >= tgt) &
             (__hip_atomic_load(F + 64 + lane, __ATOMIC_RELAXED, __HIP_MEMORY_SCOPE_AGENT) >= tgt) &
             (__hip_atomic_load(F + 128 + lane, __ATOMIC_RELAXED, __HIP_MEMORY_SCOPE_AGENT) >= tgt) &
             (__hip_atomic_load(F + 192 + lane, __ATOMIC_RELAXED, __HIP_MEMORY_SCOPE_AGENT) >= tgt);
    if (__all(ok)) break;
    __builtin_amdgcn_s_sleep(1);
  }
  asm volatile("" ::: "memory");
}
DEV void wait256x2(const unsigned* A, unsigned ta, const unsigned* B, unsigned tb, int lane) {
  while (true) {
    int ok = (__hip_atomic_load(A + lane, __ATOMIC_RELAXED, __HIP_MEMORY_SCOPE_AGENT) >= ta) &
             (__hip_atomic_load(A + 64 + lane, __ATOMIC_RELAXED, __HIP_MEMORY_SCOPE_AGENT) >= ta) &
             (__hip_atomic_load(A + 128 + lane, __ATOMIC_RELAXED, __HIP_MEMORY_SCOPE_AGENT) >= ta) &
             (__hip_atomic_load(A + 192 + lane, __ATOMIC_RELAXED, __HIP_MEMORY_SCOPE_AGENT) >= ta) &
             (__hip_atomic_load(B + lane, __ATOMIC_RELAXED, __HIP_MEMORY_SCOPE_AGENT) >= tb) &
             (__hip_atomic_load(B + 64 + lane, __ATOMIC_RELAXED, __HIP_MEMORY_SCOPE_AGENT) >= tb) &
             (__hip_atomic_load(B + 128 + lane, __ATOMIC_RELAXED, __HIP_MEMORY_SCOPE_AGENT) >= tb) &
             (__hip_atomic_load(B + 192 + lane, __ATOMIC_RELAXED, __HIP_MEMORY_SCOPE_AGENT) >= tb);
    if (__all(ok)) break;
    __builtin_amdgcn_s_sleep(1);
  }
  asm volatile("" ::: "memory");
}

// ---------------- prep: ws_src/ws_dst (W @ att vectors), bias sums ----------
__global__ void prep_small(const float* __restrict__ gat_W,
                           const float* __restrict__ att_src,
                           const float* __restrict__ att_dst,
                           const float* __restrict__ b_ih,
                           const float* __restrict__ b_hh,
                           float* __restrict__ ws_src, float* __restrict__ ws_dst,
                           float* __restrict__ bias_sum) {
  int total = 1200 + 1200 + 3 * 4096;
  for (int i = blockIdx.x * blockDim.x + threadIdx.x; i < total; i += gridDim.x * blockDim.x) {
    if (i < 1200) {
      int d = i >> 2, h = i & 3;
      float s = 0.f;
      for (int c = 0; c < kCC; ++c) s += gat_W[d * 300 + h * kCC + c] * att_src[h * kCC + c];
      ws_src[i] = s;
    } else if (i < 2400) {
      int j = i - 1200; int d = j >> 2, h = j & 3;
      float s = 0.f;
      for (int c = 0; c < kCC; ++c) s += gat_W[d * 300 + h * kCC + c] * att_dst[h * kCC + c];
      ws_dst[j] = s;
    } else {
      int j = i - 2400;
      bias_sum[j] = b_ih[j] + b_hh[j];
    }
  }
}

// ---------------- prep: bf16 W_ih0 only -------------------------------------
__global__ void wx_prep(const float* __restrict__ W_ih0, u16* __restrict__ wx0) {
  const int n0 = 4096 * 640;
  for (int i = blockIdx.x * blockDim.x + threadIdx.x; i < n0; i += gridDim.x * blockDim.x) {
    int row = i / 640, col = i - row * 640;
    float v = (col < 600) ? W_ih0[row * 600 + col] : 0.f;
    wx0[i] = f2bf(v);
  }
}

// ---------------- prep: bf16 copy of lin_W ----------------------------------
__global__ void wb_conv(const float* __restrict__ W, u16* __restrict__ Wb) {
  const long n = (long)kVG * 1024;
  long stride = (long)gridDim.x * blockDim.x * 8;
  for (long i = (long)(blockIdx.x * blockDim.x + threadIdx.x) * 8; i < n; i += stride) {
    float4 a = *(const float4*)(W + i);
    float4 b = *(const float4*)(W + i + 4);
    u16 t[8] = {f2bf(a.x), f2bf(a.y), f2bf(a.z), f2bf(a.w),
                f2bf(b.x), f2bf(b.y), f2bf(b.z), f2bf(b.w)};
    *(uint4*)(Wb + i) = *(const uint4*)t;
  }
}

// ---------------- GAT (node-0 only, factored attention) ---------------------
__global__ void __launch_bounds__(256) gat_kernel(
    const int* __restrict__ x_indices, const int* __restrict__ edge_index,
    const float* __restrict__ X, const float* __restrict__ gat_W,
    const float* __restrict__ gat_bias, const float* __restrict__ ws_src,
    const float* __restrict__ ws_dst, u16* __restrict__ sig) {
  __shared__ float xs[32][301];
  __shared__ float a_s[32][4];
  __shared__ float a_d0[4];
  __shared__ float alpha[4][32];
  __shared__ float xw[4][301];
  __shared__ int allowed[32];
  int g = blockIdx.x, tid = threadIdx.x;
  const int* idx = x_indices + g * 32;
  for (int i = tid; i < 32 * 300; i += 256) {
    int j = i / 300, d2 = i - j * 300;
    xs[j][d2] = X[(size_t)idx[j] * 300 + d2];
  }
  if (tid < 32) allowed[tid] = (tid == 0) ? 1 : 0;
  __syncthreads();
  if (tid < 128) {
    int j = tid >> 2, h = tid & 3;
    float s = 0.f;
    for (int d2 = 0; d2 < 300; ++d2) s += xs[j][d2] * ws_src[d2 * 4 + h];
    a_s[j][h] = s;
  } else if (tid < 132) {
    int h = tid - 128; float s = 0.f;
    for (int d2 = 0; d2 < 300; ++d2) s += xs[0][d2] * ws_dst[d2 * 4 + h];
    a_d0[h] = s;
  } else if (tid >= 192) {
    int e = tid - 192;
    int src = edge_index[g * 128 + e];
    int dst = edge_index[g * 128 + 64 + e];
    if (dst == 0) allowed[src] = 1;
  }
  __syncthreads();
  if (tid < 4) {
    int h = tid;
    float ev[32];
    float mx = -1e30f;
    #pragma unroll
    for (int j = 0; j < 32; ++j) {
      float v = a_d0[h] + a_s[j][h];
      v = (v > 0.f) ? v : 0.2f * v;
      v = allowed[j] ? v : -1e9f;
      ev[j] = v; mx = fmaxf(mx, v);
    }
    float ssum = 0.f;
    #pragma unroll
    for (int j = 0; j < 32; ++j) { float p = fexp(ev[j] - mx); ev[j] = p; ssum += p; }
    float inv = 1.f / ssum;
    #pragma unroll
    for (int j = 0; j < 32; ++j) alpha[h][j] = ev[j] * inv;
  }
  __syncthreads();
  for (int i = tid; i < 4 * 300; i += 256) {
    int h = i / 300, d2 = i - h * 300;
    float s = 0.f;
    #pragma unroll
    for (int j = 0; j < 32; ++j) s += alpha[h][j] * xs[j][d2];
    xw[h][d2] = s;
  }
  __syncthreads();
  int t = g % 35, b = g / 35;
  u16* srow = sig + ((size_t)t * 32 + b) * 640;
  for (int hc = tid; hc < 300; hc += 256) {
    srow[hc] = f2bf(xs[0][hc]);           // curr_emb = X[idx 0]
    int h = hc / 75;
    float s = gat_bias[hc];
    for (int d2 = 0; d2 < 300; ++d2) s += xw[h][d2] * gat_W[d2 * 300 + hc];
    srow[300 + hc] = f2bf(s);
  }
  for (int i2 = 600 + tid; i2 < 640; i2 += 256) srow[i2] = 0;  // zero pad
}

// ---------------- bulk input-gate GEMM (gll16 dbuf + swizzled LDS) ----------
// gates written INTERLEAVED: gates[m][u*4+g]  (one float4 per (m,unit))
__global__ void __launch_bounds__(256, 4) gemm_ig(
    const u16* __restrict__ A, const u16* __restrict__ Bw,
    float* __restrict__ gates, int K) {
  int bid = blockIdx.x;
  int bm = bid % 9, bn = bid / 9;
  int m0 = bm * 128, n0 = bn * 128;
  int tid = threadIdx.x, w = tid >> 6, lane = tid & 63, l15 = lane & 15, lhi = lane >> 4;
  int wm = w & 1, wn = w >> 1;
  __shared__ u16 As[2][128][32];
  __shared__ u16 Bs[2][128][32];
  int cl = ((lane & 3) ^ ((lane >> 3) & 3)) * 8;
  int am0 = m0 + w * 32 + (lane >> 2);
  int am1 = am0 + 16;
  const u16* arow0 = A + (size_t)((am0 < kM) ? am0 : 0) * K + cl;
  const u16* arow1 = A + (size_t)((am1 < kM) ? am1 : 0) * K + cl;
  int bn0r = n0 + w * 32 + (lane >> 2);
  const u16* brow0 = Bw + (size_t)bn0r * K + cl;
  const u16* brow1 = Bw + (size_t)(bn0r + 16) * K + cl;
  const int koff = (lhi ^ ((l15 >> 1) & 3)) * 8;  // read-side swizzle

  f32x4 acc[4][4];
  #pragma unroll
  for (int i = 0; i < 4; ++i)
    #pragma unroll
    for (int j = 0; j < 4; ++j) { f32x4 z = {0.f, 0.f, 0.f, 0.f}; acc[i][j] = z; }

  auto ISSUE = [&](int k0, int buf) {
    gll16(arow0 + k0, &As[buf][w * 32][0]);
    gll16(arow1 + k0, &As[buf][w * 32 + 16][0]);
    gll16(brow0 + k0, &Bs[buf][w * 32][0]);
    gll16(brow1 + k0, &Bs[buf][w * 32 + 16][0]);
  };
  int nkt = K >> 5;
  ISSUE(0, 0);
  for (int kt = 0; kt < nkt; ++kt) {
    int cur = kt & 1;
    if (kt < nkt - 1) {
      ISSUE((kt + 1) * 32, cur ^ 1);
      asm volatile("s_waitcnt vmcnt(4)" ::: "memory");
    } else {
      asm volatile("s_waitcnt vmcnt(0)" ::: "memory");
    }
    __builtin_amdgcn_s_barrier();
    __builtin_amdgcn_sched_barrier(0);
    short8 bfr[4];
    #pragma unroll
    for (int nt = 0; nt < 4; ++nt)
      bfr[nt] = *(const short8*)&Bs[cur][wn * 64 + nt * 16 + l15][koff];
    #pragma unroll
    for (int mt = 0; mt < 4; ++mt) {
      short8 af = *(const short8*)&As[cur][wm * 64 + mt * 16 + l15][koff];
      #pragma unroll
      for (int nt = 0; nt < 4; ++nt)
        acc[mt][nt] = mfma16(af, bfr[nt], acc[mt][nt]);
    }
    __builtin_amdgcn_sched_barrier(0);
    __builtin_amdgcn_s_barrier();
  }
  #pragma unroll
  for (int mt = 0; mt < 4; ++mt) {
    #pragma unroll
    for (int r = 0; r < 4; ++r) {
      int m = m0 + wm * 64 + mt * 16 + lhi * 4 + r;
      if (m < kM) {
        float* orow = gates + (size_t)m * 4096;
        #pragma unroll
        for (int nt = 0; nt < 4; ++nt) {
          int n = n0 + wn * 64 + nt * 16 + l15;
          orow[(n & 1023) * 4 + (n >> 10)] = acc[mt][nt][r];
        }
      }
    }
  }
}

// ---------------- LSTM: 5 decoupled per-wave chains, no block barriers ------
// 256 blocks x 320 threads (5 waves). Block p owns units [4p,4p+4), all layers.
//  w0: layer0 (Whh0 in 128 VGPRs, both batch halves)        -> F0
//  w1/w2: layer1 batch halves (Wih1+Whh1 from LDS)          -> F1 (handshake)
//  w3/w4: layer2 batch halves (Wih2+Whh2 from LDS)          -> F2 (handshake)
// Chains pipeline with 1-step skew; waits are producer-only flag polls.
__global__ void __launch_bounds__(320, 1) lstm_chain(
    const float* __restrict__ W_hh,      // [3][4096][1024]
    const float* __restrict__ W_ih_rest, // [2][4096][1024]
    const float* __restrict__ gates,     // [1120][1024][4] f32 (layer0 x-part)
    const float* __restrict__ bias_sum,  // [3][4096]
    u16* __restrict__ hist0, u16* __restrict__ hist1, u16* __restrict__ hist2,
    unsigned* __restrict__ F0, unsigned* __restrict__ F1,
    unsigned* __restrict__ F2) {
  const int p = blockIdx.x;            // 0..255
  const int u0 = p * 4;
  const int tid = threadIdx.x;
  const int w = tid >> 6, lane = tid & 63;
  const int c16 = lane & 15, u = lane >> 4;   // MFMA frag & pointwise roles

  __shared__ u16 wlds[4][16][1032];    // 0:Wih1 1:Whh1 2:Wih2 3:Whh2 (padded)
  __shared__ float pw[5][2][16][17];   // per-wave gate scratch
  __shared__ unsigned prog1, prog2;    // intra-block half-pair handshakes

  if (tid == 0) { prog1 = 0u; prog2 = 0u; }
  // prologue: 4 weight matrices -> LDS (16 rows each, fp32->bf16, padded rows)
  for (int i = tid; i < 4 * 16 * 128; i += 320) {
    int mat = i >> 11;
    int rem = i & 2047;
    int row = rem >> 7;
    int k8 = (rem & 127) * 8;
    size_t off = (size_t)((row >> 2) * 1024 + u0 + (row & 3)) * 1024 + k8;
    const float* src = (mat == 0) ? W_ih_rest + off
                     : (mat == 1) ? W_hh + (size_t)4096 * 1024 + off
                     : (mat == 2) ? W_ih_rest + (size_t)4096 * 1024 + off
                                  : W_hh + (size_t)2 * 4096 * 1024 + off;
    short8 v = ld8bf(src);
    *(short8*)&wlds[mat][row][k8] = v;
  }
  __syncthreads();   // one-time: weights + prog ready

  if (w == 0) {
    // ---- layer 0 chain: Whh0 in registers, both batch halves ----
    short8 rw[32];
    size_t grow = (size_t)((c16 >> 2) * 1024 + u0 + (c16 & 3)) * 1024;
    #pragma unroll
    for (int kk = 0; kk < 32; ++kk)
      rw[kk] = ld8bf(W_hh + grow + kk * 32 + u * 8);
    float bias_r[4];
    #pragma unroll
    for (int g = 0; g < 4; ++g) bias_r[g] = bias_sum[g * 1024 + u0 + u];
    float cr0 = 0.f, cr1 = 0.f;
    for (int t = 0; t < 35; ++t) {
      if (t > 0) {
        wait256(F0, (unsigned)t, lane);
        const u16* hp = hist0 + (size_t)(t - 1) * 32768;
        const u16* b0p = hp + c16 * 1024 + u * 8;
        const u16* b1p = hp + (c16 + 16) * 1024 + u * 8;
        f32x4 a0 = {0,0,0,0}, a1 = {0,0,0,0};
        #pragma unroll
        for (int kk = 0; kk < 32; ++kk) {
          a0 = mfma16(rw[kk], *(const short8*)(b0p + kk * 32), a0);
          a1 = mfma16(rw[kk], *(const short8*)(b1p + kk * 32), a1);
        }
        #pragma unroll
        for (int r = 0; r < 4; ++r) {
          pw[0][0][u * 4 + r][c16] = a0[r];
          pw[0][1][u * 4 + r][c16] = a1[r];
        }
      } else {
        #pragma unroll
        for (int r = 0; r < 4; ++r) {
          pw[0][0][u * 4 + r][c16] = 0.f;
          pw[0][1][u * 4 + r][c16] = 0.f;
        }
      }
      asm volatile("s_waitcnt lgkmcnt(0)" ::: "memory");
      __builtin_amdgcn_sched_barrier(0);
      float4 gx0 = ((const float4*)gates)[(size_t)(t * 32 + c16) * 1024 + u0 + u];
      float4 gx1 = ((const float4*)gates)[(size_t)(t * 32 + c16 + 16) * 1024 + u0 + u];
      float p00 = pw[0][0][u][c16]      + gx0.x + bias_r[0];
      float p01 = pw[0][0][4 + u][c16]  + gx0.y + bias_r[1];
      float p02 = pw[0][0][8 + u][c16]  + gx0.z + bias_r[2];
      float p03 = pw[0][0][12 + u][c16] + gx0.w + bias_r[3];
      float p10 = pw[0][1][u][c16]      + gx1.x + bias_r[0];
      float p11 = pw[0][1][4 + u][c16]  + gx1.y + bias_r[1];
      float p12 = pw[0][1][8 + u][c16]  + gx1.z + bias_r[2];
      float p13 = pw[0][1][12 + u][c16] + gx1.w + bias_r[3];
      float cc0 = fsigm(p01) * cr0 + fsigm(p00) * ftanh(p02);
      float hh0 = fsigm(p03) * ftanh(cc0); cr0 = cc0;
      float cc1 = fsigm(p11) * cr1 + fsigm(p10) * ftanh(p12);
      float hh1 = fsigm(p13) * ftanh(cc1); cr1 = cc1;
      store_u16_llc(hist0 + ((size_t)(t * 32 + c16) << 10) + u0 + u, f2bf(hh0));
      store_u16_llc(hist0 + ((size_t)(t * 32 + c16 + 16) << 10) + u0 + u, f2bf(hh1));
      asm volatile("s_waitcnt vmcnt(0)" ::: "memory");
      if (lane == 0)
        __hip_atomic_store(F0 + p, (unsigned)(t + 1),
                           __ATOMIC_RELAXED, __HIP_MEMORY_SCOPE_AGENT);
    }
  } else if (w <= 2) {
    // ---- layer 1 chain, batch half (w-1) ----
    const int bb = (w - 1) * 16;
    float bias_r[4];
    #pragma unroll
    for (int g = 0; g < 4; ++g) bias_r[g] = bias_sum[4096 + g * 1024 + u0 + u];
    float cr = 0.f;
    for (int t = 0; t < 35; ++t) {
      if (t > 0) wait256x2(F0, (unsigned)(t + 1), F1, (unsigned)t, lane);
      else       wait256(F0, 1u, lane);
      const u16* xp = hist0 + (size_t)t * 32768;
      const u16* bxp = xp + (bb + c16) * 1024 + u * 8;
      f32x4 a = {0,0,0,0};
      #pragma unroll
      for (int kk = 0; kk < 32; ++kk)
        a = mfma16(*(const short8*)&wlds[0][c16][kk * 32 + u * 8],
                   *(const short8*)(bxp + kk * 32), a);
      if (t > 0) {
        const u16* hp = hist1 + (size_t)(t - 1) * 32768;
        const u16* bhp = hp + (bb + c16) * 1024 + u * 8;
        #pragma unroll
        for (int kk = 0; kk < 32; ++kk)
          a = mfma16(*(const short8*)&wlds[1][c16][kk * 32 + u * 8],
                     *(const short8*)(bhp + kk * 32), a);
      }
      #pragma unroll
      for (int r = 0; r < 4; ++r) pw[w][0][u * 4 + r][c16] = a[r];
      asm volatile("s_waitcnt lgkmcnt(0)" ::: "memory");
      __builtin_amdgcn_sched_barrier(0);
      float q0 = pw[w][0][u][c16]      + bias_r[0];
      float q1 = pw[w][0][4 + u][c16]  + bias_r[1];
      float q2 = pw[w][0][8 + u][c16]  + bias_r[2];
      float q3 = pw[w][0][12 + u][c16] + bias_r[3];
      float cc = fsigm(q1) * cr + fsigm(q0) * ftanh(q2);
      float hh = fsigm(q3) * ftanh(cc); cr = cc;
      store_u16_llc(hist1 + ((size_t)(t * 32 + bb + c16) << 10) + u0 + u, f2bf(hh));
      asm volatile("s_waitcnt vmcnt(0)" ::: "memory");
      if (w == 1) {
        if (lane == 0)
          __hip_atomic_store(&prog1, (unsigned)(t + 1),
                             __ATOMIC_RELEASE, __HIP_MEMORY_SCOPE_WORKGROUP);
      } else {
        if (lane == 0) {
          while (__hip_atomic_load(&prog1, __ATOMIC_ACQUIRE,
                                   __HIP_MEMORY_SCOPE_WORKGROUP) < (unsigned)(t + 1))
            __builtin_amdgcn_s_sleep(1);
          __hip_atomic_store(F1 + p, (unsigned)(t + 1),
                             __ATOMIC_RELAXED, __HIP_MEMORY_SCOPE_AGENT);
        }
      }
    }
  } else {
    // ---- layer 2 chain, batch half (w-3) ----
    const int bb = (w - 3) * 16;
    float bias_r[4];
    #pragma unroll
    for (int g = 0; g < 4; ++g) bias_r[g] = bias_sum[8192 + g * 1024 + u0 + u];
    float cr = 0.f;
    for (int t = 0; t < 35; ++t) {
      if (t > 0) wait256x2(F1, (unsigned)(t + 1), F2, (unsigned)t, lane);
      else       wait256(F1, 1u, lane);
      const u16* xp = hist1 + (size_t)t * 32768;
      const u16* bxp = xp + (bb + c16) * 1024 + u * 8;
      f32x4 a = {0,0,0,0};
      #pragma unroll
      for (int kk = 0; kk < 32; ++kk)
        a = mfma16(*(const short8*)&wlds[2][c16][kk * 32 + u * 8],
                   *(const short8*)(bxp + kk * 32), a);
      if (t > 0) {
        const u16* hp = hist2 + (size_t)(t - 1) * 32768;
        const u16* bhp = hp + (bb + c16) * 1024 + u * 8;
        #pragma unroll
        for (int kk = 0; kk < 32; ++kk)
          a = mfma16(*(const short8*)&wlds[3][c16][kk * 32 + u * 8],
                     *(const short8*)(bhp + kk * 32), a);
      }
      #pragma unroll
      for (int r = 0; r < 4; ++r) pw[w][0][u * 4 + r][c16] = a[r];
      asm volatile("s_waitcnt lgkmcnt(0)" ::: "memory");
      __builtin_amdgcn_sched_barrier(0);
      float q0 = pw[w][0][u][c16]      + bias_r[0];
      float q1 = pw[w][0][4 + u][c16]  + bias_r[1];
      float q2 = pw[w][0][8 + u][c16]  + bias_r[2];
      float q3 = pw[w][0][12 + u][c16] + bias_r[3];
      float cc = fsigm(q1) * cr + fsigm(q0) * ftanh(q2);
      float hh = fsigm(q3) * ftanh(cc); cr = cc;
      store_u16_llc(hist2 + ((size_t)(t * 32 + bb + c16) << 10) + u0 + u, f2bf(hh));
      asm volatile("s_waitcnt vmcnt(0)" ::: "memory");
      if (w == 3) {
        if (lane == 0)
          __hip_atomic_store(&prog2, (unsigned)(t + 1),
                             __ATOMIC_RELEASE, __HIP_MEMORY_SCOPE_WORKGROUP);
      } else {
        if (lane == 0) {
          while (__hip_atomic_load(&prog2, __ATOMIC_ACQUIRE,
                                   __HIP_MEMORY_SCOPE_WORKGROUP) < (unsigned)(t + 1))
            __builtin_amdgcn_s_sleep(1);
          __hip_atomic_store(F2 + p, (unsigned)(t + 1),
                             __ATOMIC_RELAXED, __HIP_MEMORY_SCOPE_AGENT);
        }
      }
    }
  }
}

// ---------------- logits GEMM epilogue --------------------------------------
DEV void logits_epilogue(f32x4 (&acc)[4][4], int m0, int n0, int wm, int wn,
                         int l15, int lhi, const float* lin_b,
                         float* out, float2* partials, int bn) {
  float bcol[4]; int ncol[4];
  #pragma unroll
  for (int nt = 0; nt < 4; ++nt) {
    int n = n0 + wn * 64 + nt * 16 + l15;
    ncol[nt] = n;
    bcol[nt] = (n < kVG) ? lin_b[n] : -INFINITY;
  }
  #pragma unroll
  for (int mt = 0; mt < 4; ++mt) {
    #pragma unroll
    for (int r = 0; r < 4; ++r) {
      int m = m0 + wm * 64 + mt * 16 + lhi * 4 + r;
      float v0 = acc[mt][0][r] + bcol[0];
      float v1 = acc[mt][1][r] + bcol[1];
      float v2 = acc[mt][2][r] + bcol[2];
      float v3 = acc[mt][3][r] + bcol[3];
      bool mok = (m < kM);
      if (mok) {
        float* orow = out + (size_t)m * kVG;
        if (ncol[0] < kVG) orow[ncol[0]] = v0;
        if (ncol[1] < kVG) orow[ncol[1]] = v1;
        if (ncol[2] < kVG) orow[ncol[2]] = v2;
        if (ncol[3] < kVG) orow[ncol[3]] = v3;
      }
      float mx = fmaxf(fmaxf(v0, v1), fmaxf(v2, v3));
      #pragma unroll
      for (int d2 = 1; d2 < 16; d2 <<= 1) mx = fmaxf(mx, __shfl_xor(mx, d2, 64));
      float sv = 0.f;
      sv += (v0 > -1e30f) ? fexp(v0 - mx) : 0.f;
      sv += (v1 > -1e30f) ? fexp(v1 - mx) : 0.f;
      sv += (v2 > -1e30f) ? fexp(v2 - mx) : 0.f;
      sv += (v3 > -1e30f) ? fexp(v3 - mx) : 0.f;
      #pragma unroll
      for (int d2 = 1; d2 < 16; d2 <<= 1) sv += __shfl_xor(sv, d2, 64);
      if (mok && l15 == 0)
        partials[(size_t)m * 784 + bn * 2 + wn] = make_float2(mx, sv);
    }
  }
}

// ---------------- logits GEMM (gll16 dbuf + swizzled LDS) -------------------
__global__ void __launch_bounds__(256, 4) gemm_logits_async(
    const u16* __restrict__ hist2, const u16* __restrict__ linwb,
    const float* __restrict__ lin_b, float* __restrict__ out,
    float2* __restrict__ partials) {
  int nwg = gridDim.x, orig = blockIdx.x;
  int q = nwg >> 3, r = nwg & 7, xcd = orig & 7, off = orig >> 3;
  int bid = (xcd < r ? xcd * (q + 1) : r * (q + 1) + (xcd - r) * q) + off;
  int bm = bid % 9, bn = bid / 9;
  int m0 = bm * 128, n0 = bn * 128;
  int tid = threadIdx.x, w = tid >> 6, lane = tid & 63, l15 = lane & 15, lhi = lane >> 4;
  int wm = w & 1, wn = w >> 1;
  __shared__ u16 As[2][128][32];
  __shared__ u16 Bs[2][128][32];
  int cl = ((lane & 3) ^ ((lane >> 3) & 3)) * 8;
  int am0 = m0 + w * 32 + (lane >> 2);
  int am1 = am0 + 16;
  int mm0 = (am0 < kM) ? am0 : 0, mm1 = (am1 < kM) ? am1 : 0;
  const u16* arow0 = hist2 + (((size_t)((mm0 % 35) * 32 + mm0 / 35)) << 10) + cl;
  const u16* arow1 = hist2 + (((size_t)((mm1 % 35) * 32 + mm1 / 35)) << 10) + cl;
  int nr0 = n0 + w * 32 + (lane >> 2);
  int nn0 = (nr0 < kVG) ? nr0 : 0, nn1 = (nr0 + 16 < kVG) ? nr0 + 16 : 0;
  const u16* brow0 = linwb + ((size_t)nn0 << 10) + cl;
  const u16* brow1 = linwb + ((size_t)nn1 << 10) + cl;
  const int koff = (lhi ^ ((l15 >> 1) & 3)) * 8;

  f32x4 acc[4][4];
  #pragma unroll
  for (int i = 0; i < 4; ++i)
    #pragma unroll
    for (int j = 0; j < 4; ++j) { f32x4 z = {0.f, 0.f, 0.f, 0.f}; acc[i][j] = z; }

  auto ISSUE = [&](int k0, int buf) {
    gll16(arow0 + k0, &As[buf][w * 32][0]);
    gll16(arow1 + k0, &As[buf][w * 32 + 16][0]);
    gll16(brow0 + k0, &Bs[buf][w * 32][0]);
    gll16(brow1 + k0, &Bs[buf][w * 32 + 16][0]);
  };
  ISSUE(0, 0);
  for (int kt = 0; kt < 32; ++kt) {
    int cur = kt & 1;
    if (kt < 31) {
      ISSUE((kt + 1) * 32, cur ^ 1);
      asm volatile("s_waitcnt vmcnt(4)" ::: "memory");
    } else {
      asm volatile("s_waitcnt vmcnt(0)" ::: "memory");
    }
    __builtin_amdgcn_s_barrier();
    __builtin_amdgcn_sched_barrier(0);
    short8 bfr[4];
    #pragma unroll
    for (int nt = 0; nt < 4; ++nt)
      bfr[nt] = *(const short8*)&Bs[cur][wn * 64 + nt * 16 + l15][koff];
    #pragma unroll
    for (int mt = 0; mt < 4; ++mt) {
      short8 af = *(const short8*)&As[cur][wm * 64 + mt * 16 + l15][koff];
      #pragma unroll
      for (int nt = 0; nt < 4; ++nt)
        acc[mt][nt] = mfma16(af, bfr[nt], acc[mt][nt]);
    }
    __builtin_amdgcn_sched_barrier(0);
    __builtin_amdgcn_s_barrier();
  }
  logits_epilogue(acc, m0, n0, wm, wn, l15, lhi, lin_b, out, partials, bn);
}

// fallback (no bf16 workspace image): reg-staged, fp32 B inline-converted
__global__ void __launch_bounds__(256, 1) gemm_logits_fb(
    const u16* __restrict__ hist2, const float* __restrict__ lin_W,
    const float* __restrict__ lin_b, float* __restrict__ out,
    float2* __restrict__ partials) {
  int nwg = gridDim.x, orig = blockIdx.x;
  int q = nwg >> 3, r = nwg & 7, xcd = orig & 7, off = orig >> 3;
  int bid = (xcd < r ? xcd * (q + 1) : r * (q + 1) + (xcd - r) * q) + off;
  int bm = bid % 9, bn = bid / 9;
  int m0 = bm * 128, n0 = bn * 128;
  int tid = threadIdx.x, w = tid >> 6, lane = tid & 63, l15 = lane & 15, lhi = lane >> 4;
  int wm = w & 1, wn = w >> 1;
  __shared__ u16 As[128][40];
  __shared__ u16 Bs[128][40];
  f32x4 acc[4][4];
  #pragma unroll
  for (int i = 0; i < 4; ++i)
    #pragma unroll
    for (int j = 0; j < 4; ++j) { f32x4 z = {0.f, 0.f, 0.f, 0.f}; acc[i][j] = z; }
  for (int kt = 0; kt < 32; ++kt) {
    int k0 = kt * 32;
    #pragma unroll
    for (int q2 = 0; q2 < 2; ++q2) {
      int c = tid * 2 + q2; int row = c >> 2; int ch = c & 3;
      int m = m0 + row;
      uint4 av{0u, 0u, 0u, 0u};
      if (m < kM) {
        int b = m / 35; int t = m - b * 35;
        av = *(const uint4*)(hist2 + ((size_t)(t * 32 + b) << 10) + k0 + ch * 8);
      }
      *(uint4*)&As[row][ch * 8] = av;
      int n = n0 + row;
      uint4 bv{0u, 0u, 0u, 0u};
      if (n < kVG) {
        const float* src = lin_W + (size_t)n * 1024 + k0 + ch * 8;
        float4 f0 = *(const float4*)(src);
        float4 f1 = *(const float4*)(src + 4);
        bv.x = (unsigned)f2bf(f0.x) | ((unsigned)f2bf(f0.y) << 16);
        bv.y = (unsigned)f2bf(f0.z) | ((unsigned)f2bf(f0.w) << 16);
        bv.z = (unsigned)f2bf(f1.x) | ((unsigned)f2bf(f1.y) << 16);
        bv.w = (unsigned)f2bf(f1.z) | ((unsigned)f2bf(f1.w) << 16);
      }
      *(uint4*)&Bs[row][ch * 8] = bv;
    }
    __syncthreads();
    short8 bfr[4];
    #pragma unroll
    for (int nt = 0; nt < 4; ++nt)
      bfr[nt] = *(const short8*)&Bs[wn * 64 + nt * 16 + l15][lhi * 8];
    #pragma unroll
    for (int mt = 0; mt < 4; ++mt) {
      short8 af = *(const short8*)&As[wm * 64 + mt * 16 + l15][lhi * 8];
      #pragma unroll
      for (int nt = 0; nt < 4; ++nt)
        acc[mt][nt] = mfma16(af, bfr[nt], acc[mt][nt]);
    }
    __syncthreads();
  }
  logits_epilogue(acc, m0, n0, wm, wn, l15, lhi, lin_b, out, partials, bn);
}

// ---------------- row logsumexp reduce --------------------------------------
__global__ void reduce_rows(const float2* __restrict__ partials, float* __restrict__ lse) {
  int m = blockIdx.x, tid = threadIdx.x;
  float mx = -INFINITY, s = 0.f;
  for (int j = tid; j < 782; j += 256) {
    float2 p = partials[(size_t)m * 784 + j];
    if (p.x > mx) { s = s * fexp(mx - p.x) + p.y; mx = p.x; }
    else          { s += p.y * fexp(p.x - mx); }
  }
  for (int d = 1; d < 64; d <<= 1) {
    float omx = __shfl_xor(mx, d, 64);
    float os  = __shfl_xor(s, d, 64);
    if (omx > mx) { s = s * fexp(mx - omx) + os; mx = omx; }
    else          { s += os * fexp(omx - mx); }
  }
  __shared__ float smx[4], ssum[4];
  int w = tid >> 6;
  if ((tid & 63) == 0) { smx[w] = mx; ssum[w] = s; }
  __syncthreads();
  if (tid == 0) {
    for (int i = 1; i < 4; ++i) {
      float omx = smx[i], os = ssum[i];
      if (omx > mx) { s = s * fexp(mx - omx) + os; mx = omx; }
      else          { s += os * fexp(omx - mx); }
    }
    lse[m] = mx + logf(s);
  }
}

// ---------------- in-place log_softmax subtract -----------------------------
__global__ void sub_lse(float* __restrict__ out, const float* __restrict__ lse) {
  const int total4 = 14000000;  // 1120*50000/4
  for (int i = blockIdx.x * blockDim.x + threadIdx.x; i < total4; i += gridDim.x * blockDim.x) {
    int m = i / 12500;
    float4 v = ((float4*)out)[i];
    float L = lse[m];
    v.x -= L; v.y -= L; v.z -= L; v.w -= L;
    ((float4*)out)[i] = v;
  }
}

// ---------------- launch ----------------------------------------------------
extern "C" void kernel_launch(void* const* d_in, const int* in_sizes, int n_in,
                              void* d_out, int out_size, void* d_ws, size_t ws_size,
                              hipStream_t stream) {
  const int*   x_indices  = (const int*)d_in[0];
  const int*   edge_index = (const int*)d_in[1];
  const float* X          = (const float*)d_in[2];
  const float* gat_W      = (const float*)d_in[3];
  const float* att_src    = (const float*)d_in[4];
  const float* att_dst    = (const float*)d_in[5];
  const float* gat_bias   = (const float*)d_in[6];
  const float* W_ih0      = (const float*)d_in[7];
  const float* W_ih_rest  = (const float*)d_in[8];
  const float* W_hh       = (const float*)d_in[9];
  const float* b_ih       = (const float*)d_in[10];
  const float* b_hh       = (const float*)d_in[11];
  const float* lin_W      = (const float*)d_in[12];
  const float* lin_b      = (const float*)d_in[13];
  float* out = (float*)d_out;
  char* ws = (char*)d_ws;

  unsigned* flags    = (unsigned*)(ws + OFF_BAR);
  float*    ws_src   = (float*)(ws + OFF_WSRC);
  float*    ws_dst   = (float*)(ws + OFF_WDST);
  float*    bias_sum = (float*)(ws + OFF_BIAS);
  u16*      sig      = (u16*)(ws + OFF_SIG);
  u16*      wx0      = (u16*)(ws + OFF_WX0);
  float*    gates    = (float*)(ws + OFF_GATES);
  u16*      hist     = (u16*)(ws + OFF_HIST);
  float2*   partials = (float2*)(ws + OFF_PART);
  float*    lse      = (float*)(ws + OFF_LSE);
  u16*      linwb    = (u16*)(ws + OFF_LINWB);
  bool use_bw = (ws_size >= kNeedBW);

  u16* hist0 = hist;
  u16* hist1 = hist + (size_t)35 * 32 * 1024;
  u16* hist2 = hist + (size_t)2 * 35 * 32 * 1024;
  unsigned* F0 = flags;
  unsigned* F1 = flags + 256;
  unsigned* F2 = flags + 512;

  hipMemsetAsync(ws + OFF_BAR, 0, 4096, stream);
  prep_small<<<64, 256, 0, stream>>>(gat_W, att_src, att_dst, b_ih, b_hh,
                                     ws_src, ws_dst, bias_sum);
  wx_prep<<<512, 256, 0, stream>>>(W_ih0, wx0);
  if (use_bw) wb_conv<<<2048, 256, 0, stream>>>(lin_W, linwb);
  gat_kernel<<<kG, 256, 0, stream>>>(x_indices, edge_index, X, gat_W, gat_bias,
                                     ws_src, ws_dst, sig);
  // layer 0 input transform (bulk)
  gemm_ig<<<288, 256, 0, stream>>>(sig, wx0, gates, 640);
  // decoupled 5-chain LSTM (no block barriers, dataflow flags)
  lstm_chain<<<256, 320, 0, stream>>>(W_hh, W_ih_rest, gates, bias_sum,
                                      hist0, hist1, hist2, F0, F1, F2);
  // logits + log_softmax
  if (use_bw)
    gemm_logits_async<<<9 * 391, 256, 0, stream>>>(hist2, linwb, lin_b, out, partials);
  else
    gemm_logits_fb<<<9 * 391, 256, 0, stream>>>(hist2, lin_W, lin_b, out, partials);
  reduce_rows<<<kG, 256, 0, stream>>>(partials, lse);
  sub_lse<<<2048, 256, 0, stream>>>(out, lse);
}

// Round 17
// 877.782 us; speedup vs baseline: 1.5693x; 1.5693x over previous
//
#include <hip/hip_runtime.h>

#define DEV __device__ __forceinline__

typedef __attribute__((ext_vector_type(8))) short short8;
typedef __attribute__((ext_vector_type(4))) float f32x4;
typedef unsigned short u16;

constexpr int kV = 80000, kD = 300, kNN = 32, kEE = 64, kHH = 4, kCC = 75;
constexpr int kB = 32, kT = 35, kU = 1024, kVG = 50000;
constexpr int kG = kB * kT;          // 1120
constexpr int kM = kG;

constexpr size_t alignup(size_t x) { return (x + 255) & ~size_t(255); }
constexpr size_t OFF_BAR   = 0;       // 256 flag slots (1024 B)
constexpr size_t OFF_WSRC  = 1024;
constexpr size_t OFF_WDST  = alignup(OFF_WSRC + 1200 * 4);
constexpr size_t OFF_BIAS  = alignup(OFF_WDST + 1200 * 4);
constexpr size_t OFF_SIG   = alignup(OFF_BIAS + 3 * 4096 * 4);
constexpr size_t OFF_WX0   = alignup(OFF_SIG + (size_t)35 * 32 * 640 * 2);
constexpr size_t OFF_WX12  = alignup(OFF_WX0 + (size_t)4096 * 640 * 2);
constexpr size_t OFF_GATES = alignup(OFF_WX12 + (size_t)2 * 4096 * 1024 * 2);
constexpr size_t OFF_HIST  = alignup(OFF_GATES + (size_t)1120 * 4096 * 4);
constexpr size_t OFF_PART  = alignup(OFF_HIST + (size_t)3 * 35 * 32 * 1024 * 2);
constexpr size_t OFF_LSE   = alignup(OFF_PART + (size_t)1120 * 784 * 8);
constexpr size_t OFF_LINWB = alignup(OFF_LSE + 1120 * 4);
constexpr size_t kLinWBytes = (size_t)kVG * 1024 * 2;
constexpr size_t kNeedBW   = OFF_LINWB + kLinWBytes;

DEV u16 f2bf(float f) {
  union { float f; unsigned u; } v; v.f = f;
  unsigned r = v.u + 0x7fffu + ((v.u >> 16) & 1u);
  return (u16)(r >> 16);
}
DEV float fexp(float x) { return __builtin_amdgcn_exp2f(x * 1.4426950408889634f); }
DEV float fsigm(float x) {
  float t = __builtin_amdgcn_exp2f(-1.4426950408889634f * x);
  return __builtin_amdgcn_rcpf(1.f + t);
}
DEV float ftanh(float x) {
  float xc = fminf(fmaxf(x, -20.f), 20.f);
  float t = __builtin_amdgcn_exp2f(2.8853900817779268f * xc);
  return (t - 1.f) * __builtin_amdgcn_rcpf(t + 1.f);
}
DEV f32x4 mfma16(short8 a, short8 b, f32x4 c) {
  return __builtin_amdgcn_mfma_f32_16x16x32_bf16(a, b, c, 0, 0, 0);
}
// store a bf16 directly to the coherent LLC (bypass non-coherent per-XCD L2).
DEV void store_u16_llc(u16* p, u16 v) {
  unsigned vv = v;
  asm volatile("global_store_short %0, %1, off sc0 sc1"
               :: "v"(p), "v"(vv) : "memory");
}
// async global->LDS DMA, 16B/lane
DEV void gll16(const void* g, void* l) {
  __builtin_amdgcn_global_load_lds(
      (const __attribute__((address_space(1))) unsigned int*)g,
      (__attribute__((address_space(3))) unsigned int*)l, 16, 0, 0);
}
// load 8 fp32, convert to bf16 short8
DEV short8 ld8bf(const float* p) {
  float4 a = *(const float4*)p;
  float4 b = *(const float4*)(p + 4);
  u16 t[8] = {f2bf(a.x), f2bf(a.y), f2bf(a.z), f2bf(a.w),
              f2bf(b.x), f2bf(b.y), f2bf(b.z), f2bf(b.w)};
  return *(const short8*)t;
}

// ---------------- prep: ws_src/ws_dst (W @ att vectors), bias sums ----------
__global__ void prep_small(const float* __restrict__ gat_W,
                           const float* __restrict__ att_src,
                           const float* __restrict__ att_dst,
                           const float* __restrict__ b_ih,
                           const float* __restrict__ b_hh,
                           float* __restrict__ ws_src, float* __restrict__ ws_dst,
                           float* __restrict__ bias_sum) {
  int total = 1200 + 1200 + 3 * 4096;
  for (int i = blockIdx.x * blockDim.x + threadIdx.x; i < total; i += gridDim.x * blockDim.x) {
    if (i < 1200) {
      int d = i >> 2, h = i & 3;
      float s = 0.f;
      for (int c = 0; c < kCC; ++c) s += gat_W[d * 300 + h * kCC + c] * att_src[h * kCC + c];
      ws_src[i] = s;
    } else if (i < 2400) {
      int j = i - 1200; int d = j >> 2, h = j & 3;
      float s = 0.f;
      for (int c = 0; c < kCC; ++c) s += gat_W[d * 300 + h * kCC + c] * att_dst[h * kCC + c];
      ws_dst[j] = s;
    } else {
      int j = i - 2400;
      bias_sum[j] = b_ih[j] + b_hh[j];
    }
  }
}

// ---------------- GAT + weight conversions (role-split grid) ----------------
// blocks [0,1120): GAT graphs. blocks [1120,1120+1024): fp32->bf16 converters
// (lin_W -> linwb if non-null, W_ih0 -> wx0). BW-bound conversion overlaps
// the VALU-bound GAT instead of serializing as separate launches.
__global__ void __launch_bounds__(256) gat_conv(
    const int* __restrict__ x_indices, const int* __restrict__ edge_index,
    const float* __restrict__ X, const float* __restrict__ gat_W,
    const float* __restrict__ gat_bias, const float* __restrict__ ws_src,
    const float* __restrict__ ws_dst, u16* __restrict__ sig,
    const float* __restrict__ lin_W, u16* __restrict__ linwb,
    const float* __restrict__ W_ih0, u16* __restrict__ wx0) {
  if (blockIdx.x >= kG) {
    long cb = blockIdx.x - kG;                 // 0..1023
    long tid0 = cb * 256 + threadIdx.x;
    long stride = 1024L * 256;
    if (linwb) {
      long n8 = ((long)kVG * 1024) >> 3;
      for (long i = tid0; i < n8; i += stride) {
        long o = i * 8;
        short8 v = ld8bf(lin_W + o);
        *(short8*)(linwb + o) = v;
      }
    }
    const long n0w = 4096 * 640;
    for (long i = tid0; i < n0w; i += stride) {
      long row = i / 640, col = i - row * 640;
      wx0[i] = f2bf(col < 600 ? W_ih0[row * 600 + col] : 0.f);
    }
    return;
  }
  __shared__ float xs[32][301];
  __shared__ float a_s[32][4];
  __shared__ float a_d0[4];
  __shared__ float alpha[4][32];
  __shared__ float xw[4][301];
  __shared__ int allowed[32];
  int g = blockIdx.x, tid = threadIdx.x;
  const int* idx = x_indices + g * 32;
  for (int i = tid; i < 32 * 300; i += 256) {
    int j = i / 300, d2 = i - j * 300;
    xs[j][d2] = X[(size_t)idx[j] * 300 + d2];
  }
  if (tid < 32) allowed[tid] = (tid == 0) ? 1 : 0;
  __syncthreads();
  if (tid < 128) {
    int j = tid >> 2, h = tid & 3;
    float s = 0.f;
    for (int d2 = 0; d2 < 300; ++d2) s += xs[j][d2] * ws_src[d2 * 4 + h];
    a_s[j][h] = s;
  } else if (tid < 132) {
    int h = tid - 128; float s = 0.f;
    for (int d2 = 0; d2 < 300; ++d2) s += xs[0][d2] * ws_dst[d2 * 4 + h];
    a_d0[h] = s;
  } else if (tid >= 192) {
    int e = tid - 192;
    int src = edge_index[g * 128 + e];
    int dst = edge_index[g * 128 + 64 + e];
    if (dst == 0) allowed[src] = 1;
  }
  __syncthreads();
  if (tid < 4) {
    int h = tid;
    float ev[32];
    float mx = -1e30f;
    #pragma unroll
    for (int j = 0; j < 32; ++j) {
      float v = a_d0[h] + a_s[j][h];
      v = (v > 0.f) ? v : 0.2f * v;
      v = allowed[j] ? v : -1e9f;
      ev[j] = v; mx = fmaxf(mx, v);
    }
    float ssum = 0.f;
    #pragma unroll
    for (int j = 0; j < 32; ++j) { float p = fexp(ev[j] - mx); ev[j] = p; ssum += p; }
    float inv = 1.f / ssum;
    #pragma unroll
    for (int j = 0; j < 32; ++j) alpha[h][j] = ev[j] * inv;
  }
  __syncthreads();
  for (int i = tid; i < 4 * 300; i += 256) {
    int h = i / 300, d2 = i - h * 300;
    float s = 0.f;
    #pragma unroll
    for (int j = 0; j < 32; ++j) s += alpha[h][j] * xs[j][d2];
    xw[h][d2] = s;
  }
  __syncthreads();
  int t = g % 35, b = g / 35;
  u16* srow = sig + ((size_t)t * 32 + b) * 640;
  for (int hc = tid; hc < 300; hc += 256) {
    srow[hc] = f2bf(xs[0][hc]);           // curr_emb = X[idx 0]
    int h = hc / 75;
    float s = gat_bias[hc];
    for (int d2 = 0; d2 < 300; ++d2) s += xw[h][d2] * gat_W[d2 * 300 + hc];
    srow[300 + hc] = f2bf(s);
  }
  for (int i2 = 600 + tid; i2 < 640; i2 += 256) srow[i2] = 0;  // zero pad
}

// ---------------- bulk input-gate GEMM (gll16 dbuf + swizzled LDS) ----------
// gates written INTERLEAVED: gates[m][u*4+g]  (one float4 per (m,unit))
__global__ void __launch_bounds__(256, 4) gemm_ig(
    const u16* __restrict__ A, const u16* __restrict__ Bw,
    float* __restrict__ gates, int K) {
  int bid = blockIdx.x;
  int bm = bid % 9, bn = bid / 9;
  int m0 = bm * 128, n0 = bn * 128;
  int tid = threadIdx.x, w = tid >> 6, lane = tid & 63, l15 = lane & 15, lhi = lane >> 4;
  int wm = w & 1, wn = w >> 1;
  __shared__ u16 As[2][128][32];
  __shared__ u16 Bs[2][128][32];
  int cl = ((lane & 3) ^ ((lane >> 3) & 3)) * 8;
  int am0 = m0 + w * 32 + (lane >> 2);
  int am1 = am0 + 16;
  const u16* arow0 = A + (size_t)((am0 < kM) ? am0 : 0) * K + cl;
  const u16* arow1 = A + (size_t)((am1 < kM) ? am1 : 0) * K + cl;
  int bn0r = n0 + w * 32 + (lane >> 2);
  const u16* brow0 = Bw + (size_t)bn0r * K + cl;
  const u16* brow1 = Bw + (size_t)(bn0r + 16) * K + cl;
  const int koff = (lhi ^ ((l15 >> 1) & 3)) * 8;  // read-side swizzle

  f32x4 acc[4][4];
  #pragma unroll
  for (int i = 0; i < 4; ++i)
    #pragma unroll
    for (int j = 0; j < 4; ++j) { f32x4 z = {0.f, 0.f, 0.f, 0.f}; acc[i][j] = z; }

  auto ISSUE = [&](int k0, int buf) {
    gll16(arow0 + k0, &As[buf][w * 32][0]);
    gll16(arow1 + k0, &As[buf][w * 32 + 16][0]);
    gll16(brow0 + k0, &Bs[buf][w * 32][0]);
    gll16(brow1 + k0, &Bs[buf][w * 32 + 16][0]);
  };
  int nkt = K >> 5;
  ISSUE(0, 0);
  for (int kt = 0; kt < nkt; ++kt) {
    int cur = kt & 1;
    if (kt < nkt - 1) {
      ISSUE((kt + 1) * 32, cur ^ 1);
      asm volatile("s_waitcnt vmcnt(4)" ::: "memory");
    } else {
      asm volatile("s_waitcnt vmcnt(0)" ::: "memory");
    }
    __builtin_amdgcn_s_barrier();
    __builtin_amdgcn_sched_barrier(0);
    short8 bfr[4];
    #pragma unroll
    for (int nt = 0; nt < 4; ++nt)
      bfr[nt] = *(const short8*)&Bs[cur][wn * 64 + nt * 16 + l15][koff];
    #pragma unroll
    for (int mt = 0; mt < 4; ++mt) {
      short8 af = *(const short8*)&As[cur][wm * 64 + mt * 16 + l15][koff];
      #pragma unroll
      for (int nt = 0; nt < 4; ++nt)
        acc[mt][nt] = mfma16(af, bfr[nt], acc[mt][nt]);
    }
    __builtin_amdgcn_sched_barrier(0);
    __builtin_amdgcn_s_barrier();
  }
  #pragma unroll
  for (int mt = 0; mt < 4; ++mt) {
    #pragma unroll
    for (int r = 0; r < 4; ++r) {
      int m = m0 + wm * 64 + mt * 16 + lhi * 4 + r;
      if (m < kM) {
        float* orow = gates + (size_t)m * 4096;
        #pragma unroll
        for (int nt = 0; nt < 4; ++nt) {
          int n = n0 + wn * 64 + nt * 16 + l15;
          orow[(n & 1023) * 4 + (n >> 10)] = acc[mt][nt][r];
        }
      }
    }
  }
}

// ---------------- fused 3-layer LSTM wavefront, wave-specialized ------------
// (round-15 structure: best measured. 256 blocks x 512 threads, 37 supersteps)
__global__ void __launch_bounds__(512, 1) lstm_fused012(
    const float* __restrict__ W_hh,      // [3][4096][1024]
    const float* __restrict__ W_ih_rest, // [2][4096][1024]
    const float* __restrict__ gates,     // [1120][1024][4] f32 (layer0 x-part)
    const float* __restrict__ bias_sum,  // [3][4096]
    u16* __restrict__ hist0, u16* __restrict__ hist1, u16* __restrict__ hist2,
    unsigned* __restrict__ flags) {
  const int p = blockIdx.x;            // 0..255
  const int u0 = p * 4;
  const int tid = threadIdx.x;
  const int w = tid >> 6, lane = tid & 63, l15 = lane & 15, lhi = lane >> 4;
  const int khalf = w & 1;
  const int job = w >> 1;              // 0:L0H 1:L1X 2:L1H+L2X 3:L2H
  const int kbase = khalf * 512;
  __shared__ float pred0[2][16][33];
  __shared__ float pred1[4][16][33];
  __shared__ float pred2[4][16][33];

  const int grow = (l15 >> 2) * 1024 + u0 + (l15 & 3);  // global weight row
  size_t rowoff = (size_t)grow * 1024 + kbase + lhi * 8;
  const float* m1;
  const float* m2 = W_ih_rest + (size_t)4096 * 1024 + rowoff;  // Wih2 (job2)
  if (job == 0)      m1 = W_hh + rowoff;
  else if (job == 1) m1 = W_ih_rest + rowoff;
  else if (job == 2) m1 = W_hh + (size_t)4096 * 1024 + rowoff;
  else               m1 = W_hh + (size_t)2 * 4096 * 1024 + rowoff;
  short8 r1[16], r2[16];
  #pragma unroll
  for (int kk = 0; kk < 16; ++kk) r1[kk] = ld8bf(m1 + kk * 32);
  if (job == 2) {
    #pragma unroll
    for (int kk = 0; kk < 16; ++kk) r2[kk] = ld8bf(m2 + kk * 32);
  }

  const int pw_layer = tid >> 7;       // 3 = none
  const int pb = (tid & 127) >> 2, pj = tid & 3;
  float bias_r[4] = {0.f, 0.f, 0.f, 0.f};
  if (pw_layer < 3) {
    #pragma unroll
    for (int g = 0; g < 4; ++g)
      bias_r[g] = bias_sum[pw_layer * 4096 + g * 1024 + u0 + pj];
  }
  float c_reg = 0.f;
  const unsigned* f0p = flags + khalf * 128 + lane;   // this wave's producers
  __syncthreads();

  for (int s = 0; s < 37; ++s) {
    bool active; const u16* hsrc;
    if (job == 0)      { active = (s >= 1 && s < 35);  hsrc = hist0 + (size_t)(s - 1) * 32 * 1024; }
    else if (job == 1) { active = (s >= 1 && s <= 35); hsrc = hist0 + (size_t)(s - 1) * 32 * 1024; }
    else if (job == 2) { active = (s >= 2 && s <= 36); hsrc = hist1 + (size_t)(s - 2) * 32 * 1024; }
    else               { active = (s >= 3 && s <= 36); hsrc = hist2 + (size_t)(s - 3) * 32 * 1024; }
    if (active) {
      unsigned tgt = (unsigned)s;
      while (!__all((int)((__hip_atomic_load(f0p, __ATOMIC_RELAXED,
                                             __HIP_MEMORY_SCOPE_AGENT) >= tgt) &
                          (__hip_atomic_load(f0p + 64, __ATOMIC_RELAXED,
                                             __HIP_MEMORY_SCOPE_AGENT) >= tgt))))
        __builtin_amdgcn_s_sleep(1);
      asm volatile("" ::: "memory");   // pin h loads behind the wait
    }
    f32x4 a0 = {0,0,0,0}, a1 = {0,0,0,0}, a2 = {0,0,0,0}, a3 = {0,0,0,0};
    if (active) {
      const u16* b0p = hsrc + l15 * 1024 + kbase + lhi * 8;
      const u16* b1p = hsrc + (l15 + 16) * 1024 + kbase + lhi * 8;
      if (job == 2) {
        #pragma unroll
        for (int kk = 0; kk < 16; ++kk) {
          short8 b0 = *(const short8*)(b0p + kk * 32);
          short8 b1 = *(const short8*)(b1p + kk * 32);
          a0 = mfma16(r1[kk], b0, a0);
          a1 = mfma16(r1[kk], b1, a1);
          a2 = mfma16(r2[kk], b0, a2);
          a3 = mfma16(r2[kk], b1, a3);
        }
      } else {
        #pragma unroll
        for (int kk = 0; kk < 16; ++kk) {
          short8 b0 = *(const short8*)(b0p + kk * 32);
          short8 b1 = *(const short8*)(b1p + kk * 32);
          a0 = mfma16(r1[kk], b0, a0);
          a1 = mfma16(r1[kk], b1, a1);
        }
      }
    }
    #pragma unroll
    for (int r = 0; r < 4; ++r) {
      int row = lhi * 4 + r;
      if (job == 0) {
        pred0[khalf][row][l15] = a0[r];      pred0[khalf][row][l15 + 16] = a1[r];
      } else if (job == 1) {
        pred1[khalf][row][l15] = a0[r];      pred1[khalf][row][l15 + 16] = a1[r];
      } else if (job == 2) {
        pred1[2 + khalf][row][l15] = a0[r];  pred1[2 + khalf][row][l15 + 16] = a1[r];
        pred2[khalf][row][l15] = a2[r];      pred2[khalf][row][l15 + 16] = a3[r];
      } else {
        pred2[2 + khalf][row][l15] = a0[r];  pred2[2 + khalf][row][l15 + 16] = a1[r];
      }
    }
    __syncthreads();
    bool act = (pw_layer == 0) ? (s < 35)
             : (pw_layer == 1) ? (s >= 1 && s <= 35)
             : (pw_layer == 2) ? (s >= 2 && s <= 36) : false;
    if (act) {
      float pre[4];
      if (pw_layer == 0) {
        #pragma unroll
        for (int g = 0; g < 4; ++g) {
          int row = g * 4 + pj;
          pre[g] = pred0[0][row][pb] + pred0[1][row][pb];
        }
        float4 gx = ((const float4*)gates)[(size_t)(s * 32 + pb) * 1024 + u0 + pj];
        pre[0] += gx.x; pre[1] += gx.y; pre[2] += gx.z; pre[3] += gx.w;
      } else if (pw_layer == 1) {
        #pragma unroll
        for (int g = 0; g < 4; ++g) {
          int row = g * 4 + pj;
          pre[g] = pred1[0][row][pb] + pred1[1][row][pb] +
                   pred1[2][row][pb] + pred1[3][row][pb];
        }
      } else {
        #pragma unroll
        for (int g = 0; g < 4; ++g) {
          int row = g * 4 + pj;
          pre[g] = pred2[0][row][pb] + pred2[1][row][pb] +
                   pred2[2][row][pb] + pred2[3][row][pb];
        }
      }
      float iv = pre[0] + bias_r[0];
      float fv = pre[1] + bias_r[1];
      float gv = pre[2] + bias_r[2];
      float ov = pre[3] + bias_r[3];
      float cc = fsigm(fv) * c_reg + fsigm(iv) * ftanh(gv);
      float hh = fsigm(ov) * ftanh(cc);
      c_reg = cc;
      int t = s - pw_layer;
      u16* dst = (pw_layer == 0) ? hist0 : (pw_layer == 1) ? hist1 : hist2;
      store_u16_llc(dst + ((size_t)(t * 32 + pb) << 10) + u0 + pj, f2bf(hh));
    }
    __syncthreads();   // drains LLC stores + pred reuse safety
    if (s < 36 && tid == 0)
      __hip_atomic_store(flags + p, (unsigned)(s + 1),
                         __ATOMIC_RELAXED, __HIP_MEMORY_SCOPE_AGENT);
  }
}

// ---------------- logits GEMM, 128x256 tile (gll16 dbuf + swizzled LDS) -----
__global__ void __launch_bounds__(256, 2) gemm_logits_async(
    const u16* __restrict__ hist2, const u16* __restrict__ linwb,
    const float* __restrict__ lin_b, float* __restrict__ out,
    float2* __restrict__ partials) {
  int nwg = gridDim.x, orig = blockIdx.x;
  int q = nwg >> 3, r = nwg & 7, xcd = orig & 7, off = orig >> 3;
  int bid = (xcd < r ? xcd * (q + 1) : r * (q + 1) + (xcd - r) * q) + off;
  int bm = bid % 9, bn = bid / 9;
  int m0 = bm * 128, n0 = bn * 256;
  int tid = threadIdx.x, w = tid >> 6, lane = tid & 63, l15 = lane & 15, lhi = lane >> 4;
  int wm = w & 1, wn = w >> 1;
  __shared__ u16 As[2][128][32];
  __shared__ u16 Bs[2][256][32];
  int cl = ((lane & 3) ^ ((lane >> 3) & 3)) * 8;
  // A rows: wave stages [w*32, w*32+32)
  int am0 = m0 + w * 32 + (lane >> 2);
  int am1 = am0 + 16;
  int mm0 = (am0 < kM) ? am0 : 0, mm1 = (am1 < kM) ? am1 : 0;
  const u16* arow0 = hist2 + (((size_t)((mm0 % 35) * 32 + mm0 / 35)) << 10) + cl;
  const u16* arow1 = hist2 + (((size_t)((mm1 % 35) * 32 + mm1 / 35)) << 10) + cl;
  // B rows: wave stages [w*64, w*64+64) (4 x 16 rows)
  const u16* browq[4];
  #pragma unroll
  for (int q2 = 0; q2 < 4; ++q2) {
    int nr = n0 + w * 64 + q2 * 16 + (lane >> 2);
    int nn = (nr < kVG) ? nr : 0;
    browq[q2] = linwb + ((size_t)nn << 10) + cl;
  }
  const int koff = (lhi ^ ((l15 >> 1) & 3)) * 8;

  f32x4 acc[4][8];
  #pragma unroll
  for (int i = 0; i < 4; ++i)
    #pragma unroll
    for (int j = 0; j < 8; ++j) { f32x4 z = {0.f, 0.f, 0.f, 0.f}; acc[i][j] = z; }

  auto ISSUE = [&](int k0, int buf) {
    gll16(arow0 + k0, &As[buf][w * 32][0]);
    gll16(arow1 + k0, &As[buf][w * 32 + 16][0]);
    #pragma unroll
    for (int q2 = 0; q2 < 4; ++q2)
      gll16(browq[q2] + k0, &Bs[buf][w * 64 + q2 * 16][0]);
  };
  ISSUE(0, 0);
  for (int kt = 0; kt < 32; ++kt) {
    int cur = kt & 1;
    if (kt < 31) {
      ISSUE((kt + 1) * 32, cur ^ 1);
      asm volatile("s_waitcnt vmcnt(6)" ::: "memory");
    } else {
      asm volatile("s_waitcnt vmcnt(0)" ::: "memory");
    }
    __builtin_amdgcn_s_barrier();
    __builtin_amdgcn_sched_barrier(0);
    short8 bfr[8];
    #pragma unroll
    for (int nt = 0; nt < 8; ++nt)
      bfr[nt] = *(const short8*)&Bs[cur][wn * 128 + nt * 16 + l15][koff];
    #pragma unroll
    for (int mt = 0; mt < 4; ++mt) {
      short8 af = *(const short8*)&As[cur][wm * 64 + mt * 16 + l15][koff];
      #pragma unroll
      for (int nt = 0; nt < 8; ++nt)
        acc[mt][nt] = mfma16(af, bfr[nt], acc[mt][nt]);
    }
    __builtin_amdgcn_sched_barrier(0);
    __builtin_amdgcn_s_barrier();
  }
  // epilogue: store logits + per-(row, 64-col-group) max/sumexp partials
  float bcol[8]; int ncol[8];
  #pragma unroll
  for (int nt = 0; nt < 8; ++nt) {
    int n = n0 + wn * 128 + nt * 16 + l15;
    ncol[nt] = n;
    bcol[nt] = (n < kVG) ? lin_b[n] : -INFINITY;
  }
  #pragma unroll
  for (int mt = 0; mt < 4; ++mt) {
    #pragma unroll
    for (int r = 0; r < 4; ++r) {
      int m = m0 + wm * 64 + mt * 16 + lhi * 4 + r;
      bool mok = (m < kM);
      float v[8];
      #pragma unroll
      for (int nt = 0; nt < 8; ++nt) v[nt] = acc[mt][nt][r] + bcol[nt];
      if (mok) {
        float* orow = out + (size_t)m * kVG;
        #pragma unroll
        for (int nt = 0; nt < 8; ++nt)
          if (ncol[nt] < kVG) orow[ncol[nt]] = v[nt];
      }
      #pragma unroll
      for (int half = 0; half < 2; ++half) {
        float v0 = v[half * 4], v1 = v[half * 4 + 1];
        float v2 = v[half * 4 + 2], v3 = v[half * 4 + 3];
        float mx = fmaxf(fmaxf(v0, v1), fmaxf(v2, v3));
        #pragma unroll
        for (int d2 = 1; d2 < 16; d2 <<= 1) mx = fmaxf(mx, __shfl_xor(mx, d2, 64));
        float sv = 0.f;
        sv += (v0 > -1e30f) ? fexp(v0 - mx) : 0.f;
        sv += (v1 > -1e30f) ? fexp(v1 - mx) : 0.f;
        sv += (v2 > -1e30f) ? fexp(v2 - mx) : 0.f;
        sv += (v3 > -1e30f) ? fexp(v3 - mx) : 0.f;
        #pragma unroll
        for (int d2 = 1; d2 < 16; d2 <<= 1) sv += __shfl_xor(sv, d2, 64);
        if (mok && l15 == 0)
          partials[(size_t)m * 784 + bn * 4 + wn * 2 + half] = make_float2(mx, sv);
      }
    }
  }
}

// fallback (no bf16 workspace image): reg-staged, fp32 B inline-converted
__global__ void __launch_bounds__(256, 1) gemm_logits_fb(
    const u16* __restrict__ hist2, const float* __restrict__ lin_W,
    const float* __restrict__ lin_b, float* __restrict__ out,
    float2* __restrict__ partials) {
  int nwg = gridDim.x, orig = blockIdx.x;
  int q = nwg >> 3, r = nwg & 7, xcd = orig & 7, off = orig >> 3;
  int bid = (xcd < r ? xcd * (q + 1) : r * (q + 1) + (xcd - r) * q) + off;
  int bm = bid % 9, bn = bid / 9;
  int m0 = bm * 128, n0 = bn * 128;
  int tid = threadIdx.x, w = tid >> 6, lane = tid & 63, l15 = lane & 15, lhi = lane >> 4;
  int wm = w & 1, wn = w >> 1;
  __shared__ u16 As[128][40];
  __shared__ u16 Bs[128][40];
  f32x4 acc[4][4];
  #pragma unroll
  for (int i = 0; i < 4; ++i)
    #pragma unroll
    for (int j = 0; j < 4; ++j) { f32x4 z = {0.f, 0.f, 0.f, 0.f}; acc[i][j] = z; }
  for (int kt = 0; kt < 32; ++kt) {
    int k0 = kt * 32;
    #pragma unroll
    for (int q2 = 0; q2 < 2; ++q2) {
      int c = tid * 2 + q2; int row = c >> 2; int ch = c & 3;
      int m = m0 + row;
      uint4 av{0u, 0u, 0u, 0u};
      if (m < kM) {
        int b = m / 35; int t = m - b * 35;
        av = *(const uint4*)(hist2 + ((size_t)(t * 32 + b) << 10) + k0 + ch * 8);
      }
      *(uint4*)&As[row][ch * 8] = av;
      int n = n0 + row;
      uint4 bv{0u, 0u, 0u, 0u};
      if (n < kVG) {
        const float* src = lin_W + (size_t)n * 1024 + k0 + ch * 8;
        float4 f0 = *(const float4*)(src);
        float4 f1 = *(const float4*)(src + 4);
        bv.x = (unsigned)f2bf(f0.x) | ((unsigned)f2bf(f0.y) << 16);
        bv.y = (unsigned)f2bf(f0.z) | ((unsigned)f2bf(f0.w) << 16);
        bv.z = (unsigned)f2bf(f1.x) | ((unsigned)f2bf(f1.y) << 16);
        bv.w = (unsigned)f2bf(f1.z) | ((unsigned)f2bf(f1.w) << 16);
      }
      *(uint4*)&Bs[row][ch * 8] = bv;
    }
    __syncthreads();
    short8 bfr[4];
    #pragma unroll
    for (int nt = 0; nt < 4; ++nt)
      bfr[nt] = *(const short8*)&Bs[wn * 64 + nt * 16 + l15][lhi * 8];
    #pragma unroll
    for (int mt = 0; mt < 4; ++mt) {
      short8 af = *(const short8*)&As[wm * 64 + mt * 16 + l15][lhi * 8];
      #pragma unroll
      for (int nt = 0; nt < 4; ++nt)
        acc[mt][nt] = mfma16(af, bfr[nt], acc[mt][nt]);
    }
    __syncthreads();
  }
  float bcol[4]; int ncol[4];
  #pragma unroll
  for (int nt = 0; nt < 4; ++nt) {
    int n = n0 + wn * 64 + nt * 16 + l15;
    ncol[nt] = n;
    bcol[nt] = (n < kVG) ? lin_b[n] : -INFINITY;
  }
  #pragma unroll
  for (int mt = 0; mt < 4; ++mt) {
    #pragma unroll
    for (int r = 0; r < 4; ++r) {
      int m = m0 + wm * 64 + mt * 16 + lhi * 4 + r;
      float v0 = acc[mt][0][r] + bcol[0];
      float v1 = acc[mt][1][r] + bcol[1];
      float v2 = acc[mt][2][r] + bcol[2];
      float v3 = acc[mt][3][r] + bcol[3];
      bool mok = (m < kM);
      if (mok) {
        float* orow = out + (size_t)m * kVG;
        if (ncol[0] < kVG) orow[ncol[0]] = v0;
        if (ncol[1] < kVG) orow[ncol[1]] = v1;
        if (ncol[2] < kVG) orow[ncol[2]] = v2;
        if (ncol[3] < kVG) orow[ncol[3]] = v3;
      }
      float mx = fmaxf(fmaxf(v0, v1), fmaxf(v2, v3));
      #pragma unroll
      for (int d2 = 1; d2 < 16; d2 <<= 1) mx = fmaxf(mx, __shfl_xor(mx, d2, 64));
      float sv = 0.f;
      sv += (v0 > -1e30f) ? fexp(v0 - mx) : 0.f;
      sv += (v1 > -1e30f) ? fexp(v1 - mx) : 0.f;
      sv += (v2 > -1e30f) ? fexp(v2 - mx) : 0.f;
      sv += (v3 > -1e30f) ? fexp(v3 - mx) : 0.f;
      #pragma unroll
      for (int d2 = 1; d2 < 16; d2 <<= 1) sv += __shfl_xor(sv, d2, 64);
      if (mok && l15 == 0)
        partials[(size_t)m * 784 + bn * 2 + wn] = make_float2(mx, sv);
    }
  }
}

// ---------------- row logsumexp reduce --------------------------------------
__global__ void reduce_rows(const float2* __restrict__ partials, float* __restrict__ lse) {
  int m = blockIdx.x, tid = threadIdx.x;
  float mx = -INFINITY, s = 0.f;
  for (int j = tid; j < 782; j += 256) {
    float2 p = partials[(size_t)m * 784 + j];
    if (p.x > mx) { s = s * fexp(mx - p.x) + p.y; mx = p.x; }
    else          { s += p.y * fexp(p.x - mx); }
  }
  for (int d = 1; d < 64; d <<= 1) {
    float omx = __shfl_xor(mx, d, 64);
    float os  = __shfl_xor(s, d, 64);
    if (omx > mx) { s = s * fexp(mx - omx) + os; mx = omx; }
    else          { s += os * fexp(omx - mx); }
  }
  __shared__ float smx[4], ssum[4];
  int w = tid >> 6;
  if ((tid & 63) == 0) { smx[w] = mx; ssum[w] = s; }
  __syncthreads();
  if (tid == 0) {
    for (int i = 1; i < 4; ++i) {
      float omx = smx[i], os = ssum[i];
      if (omx > mx) { s = s * fexp(mx - omx) + os; mx = omx; }
      else          { s += os * fexp(omx - mx); }
    }
    lse[m] = mx + logf(s);
  }
}

// ---------------- in-place log_softmax subtract -----------------------------
__global__ void sub_lse(float* __restrict__ out, const float* __restrict__ lse) {
  const int total4 = 14000000;  // 1120*50000/4
  for (int i = blockIdx.x * blockDim.x + threadIdx.x; i < total4; i += gridDim.x * blockDim.x) {
    int m = i / 12500;
    float4 v = ((float4*)out)[i];
    float L = lse[m];
    v.x -= L; v.y -= L; v.z -= L; v.w -= L;
    ((float4*)out)[i] = v;
  }
}

// ---------------- launch ----------------------------------------------------
extern "C" void kernel_launch(void* const* d_in, const int* in_sizes, int n_in,
                              void* d_out, int out_size, void* d_ws, size_t ws_size,
                              hipStream_t stream) {
  const int*   x_indices  = (const int*)d_in[0];
  const int*   edge_index = (const int*)d_in[1];
  const float* X          = (const float*)d_in[2];
  const float* gat_W      = (const float*)d_in[3];
  const float* att_src    = (const float*)d_in[4];
  const float* att_dst    = (const float*)d_in[5];
  const float* gat_bias   = (const float*)d_in[6];
  const float* W_ih0      = (const float*)d_in[7];
  const float* W_ih_rest  = (const float*)d_in[8];
  const float* W_hh       = (const float*)d_in[9];
  const float* b_ih       = (const float*)d_in[10];
  const float* b_hh       = (const float*)d_in[11];
  const float* lin_W      = (const float*)d_in[12];
  const float* lin_b      = (const float*)d_in[13];
  float* out = (float*)d_out;
  char* ws = (char*)d_ws;

  unsigned* flags    = (unsigned*)(ws + OFF_BAR);
  float*    ws_src   = (float*)(ws + OFF_WSRC);
  float*    ws_dst   = (float*)(ws + OFF_WDST);
  float*    bias_sum = (float*)(ws + OFF_BIAS);
  u16*      sig      = (u16*)(ws + OFF_SIG);
  u16*      wx0      = (u16*)(ws + OFF_WX0);
  float*    gates    = (float*)(ws + OFF_GATES);
  u16*      hist     = (u16*)(ws + OFF_HIST);
  float2*   partials = (float2*)(ws + OFF_PART);
  float*    lse      = (float*)(ws + OFF_LSE);
  u16*      linwb    = (u16*)(ws + OFF_LINWB);
  bool use_bw = (ws_size >= kNeedBW);

  u16* hist0 = hist;
  u16* hist1 = hist + (size_t)35 * 32 * 1024;
  u16* hist2 = hist + (size_t)2 * 35 * 32 * 1024;

  hipMemsetAsync(ws + OFF_BAR, 0, 1024, stream);
  prep_small<<<64, 256, 0, stream>>>(gat_W, att_src, att_dst, b_ih, b_hh,
                                     ws_src, ws_dst, bias_sum);
  // GAT + weight conversions fused (role-split grid)
  gat_conv<<<kG + 1024, 256, 0, stream>>>(
      x_indices, edge_index, X, gat_W, gat_bias, ws_src, ws_dst, sig,
      lin_W, use_bw ? linwb : nullptr, W_ih0, wx0);
  // layer 0 input transform (bulk)
  gemm_ig<<<288, 256, 0, stream>>>(sig, wx0, gates, 640);
  // fused 3-layer wavefront (37 supersteps, wave-specialized, dataflow flags)
  lstm_fused012<<<256, 512, 0, stream>>>(W_hh, W_ih_rest, gates, bias_sum,
                                         hist0, hist1, hist2, flags);
  // logits + log_softmax
  if (use_bw)
    gemm_logits_async<<<9 * 196, 256, 0, stream>>>(hist2, linwb, lin_b, out, partials);
  else
    gemm_logits_fb<<<9 * 391, 256, 0, stream>>>(hist2, lin_W, lin_b, out, partials);
  reduce_rows<<<kG, 256, 0, stream>>>(partials, lse);
  sub_lse<<<2048, 256, 0, stream>>>(out, lse);
}

// Round 18
// 864.158 us; speedup vs baseline: 1.5941x; 1.0158x over previous
//
#include <hip/hip_runtime.h>

#define DEV __device__ __forceinline__

typedef __attribute__((ext_vector_type(8))) short short8;
typedef __attribute__((ext_vector_type(4))) float f32x4;
typedef unsigned short u16;

constexpr int kV = 80000, kD = 300, kNN = 32, kEE = 64, kHH = 4, kCC = 75;
constexpr int kB = 32, kT = 35, kU = 1024, kVG = 50000;
constexpr int kG = kB * kT;          // 1120
constexpr int kM = kG;

constexpr size_t alignup(size_t x) { return (x + 255) & ~size_t(255); }
constexpr size_t OFF_BAR   = 0;       // 128 flag slots (1024 B)
constexpr size_t OFF_WSRC  = 1024;
constexpr size_t OFF_WDST  = alignup(OFF_WSRC + 1200 * 4);
constexpr size_t OFF_BIAS  = alignup(OFF_WDST + 1200 * 4);
constexpr size_t OFF_SIG   = alignup(OFF_BIAS + 3 * 4096 * 4);
constexpr size_t OFF_WX0   = alignup(OFF_SIG + (size_t)35 * 32 * 640 * 2);
constexpr size_t OFF_WX12  = alignup(OFF_WX0 + (size_t)4096 * 640 * 2);
constexpr size_t OFF_GATES = alignup(OFF_WX12 + (size_t)2 * 4096 * 1024 * 2);
constexpr size_t OFF_HIST  = alignup(OFF_GATES + (size_t)1120 * 4096 * 4);
constexpr size_t OFF_PART  = alignup(OFF_HIST + (size_t)3 * 35 * 32 * 1024 * 2);
constexpr size_t OFF_LSE   = alignup(OFF_PART + (size_t)1120 * 784 * 8);
constexpr size_t OFF_LINWB = alignup(OFF_LSE + 1120 * 4);
constexpr size_t kLinWBytes = (size_t)kVG * 1024 * 2;
constexpr size_t kNeedBW   = OFF_LINWB + kLinWBytes;

DEV u16 f2bf(float f) {
  union { float f; unsigned u; } v; v.f = f;
  unsigned r = v.u + 0x7fffu + ((v.u >> 16) & 1u);
  return (u16)(r >> 16);
}
DEV float fexp(float x) { return __builtin_amdgcn_exp2f(x * 1.4426950408889634f); }
DEV float fsigm(float x) {
  float t = __builtin_amdgcn_exp2f(-1.4426950408889634f * x);
  return __builtin_amdgcn_rcpf(1.f + t);
}
DEV float ftanh(float x) {
  float xc = fminf(fmaxf(x, -20.f), 20.f);
  float t = __builtin_amdgcn_exp2f(2.8853900817779268f * xc);
  return (t - 1.f) * __builtin_amdgcn_rcpf(t + 1.f);
}
DEV f32x4 mfma16(short8 a, short8 b, f32x4 c) {
  return __builtin_amdgcn_mfma_f32_16x16x32_bf16(a, b, c, 0, 0, 0);
}
// store a bf16 directly to the coherent LLC (bypass non-coherent per-XCD L2).
DEV void store_u16_llc(u16* p, u16 v) {
  unsigned vv = v;
  asm volatile("global_store_short %0, %1, off sc0 sc1"
               :: "v"(p), "v"(vv) : "memory");
}
// async global->LDS DMA, 16B/lane
DEV void gll16(const void* g, void* l) {
  __builtin_amdgcn_global_load_lds(
      (const __attribute__((address_space(1))) unsigned int*)g,
      (__attribute__((address_space(3))) unsigned int*)l, 16, 0, 0);
}
// load 8 fp32, convert to bf16 short8
DEV short8 ld8bf(const float* p) {
  float4 a = *(const float4*)p;
  float4 b = *(const float4*)(p + 4);
  u16 t[8] = {f2bf(a.x), f2bf(a.y), f2bf(a.z), f2bf(a.w),
              f2bf(b.x), f2bf(b.y), f2bf(b.z), f2bf(b.w)};
  return *(const short8*)t;
}

// ---------------- prep: ws_src/ws_dst (W @ att vectors), bias sums ----------
__global__ void prep_small(const float* __restrict__ gat_W,
                           const float* __restrict__ att_src,
                           const float* __restrict__ att_dst,
                           const float* __restrict__ b_ih,
                           const float* __restrict__ b_hh,
                           float* __restrict__ ws_src, float* __restrict__ ws_dst,
                           float* __restrict__ bias_sum) {
  int total = 1200 + 1200 + 3 * 4096;
  for (int i = blockIdx.x * blockDim.x + threadIdx.x; i < total; i += gridDim.x * blockDim.x) {
    if (i < 1200) {
      int d = i >> 2, h = i & 3;
      float s = 0.f;
      for (int c = 0; c < kCC; ++c) s += gat_W[d * 300 + h * kCC + c] * att_src[h * kCC + c];
      ws_src[i] = s;
    } else if (i < 2400) {
      int j = i - 1200; int d = j >> 2, h = j & 3;
      float s = 0.f;
      for (int c = 0; c < kCC; ++c) s += gat_W[d * 300 + h * kCC + c] * att_dst[h * kCC + c];
      ws_dst[j] = s;
    } else {
      int j = i - 2400;
      bias_sum[j] = b_ih[j] + b_hh[j];
    }
  }
}

// ---------------- GAT + weight conversions (role-split grid) ----------------
__global__ void __launch_bounds__(256) gat_conv(
    const int* __restrict__ x_indices, const int* __restrict__ edge_index,
    const float* __restrict__ X, const float* __restrict__ gat_W,
    const float* __restrict__ gat_bias, const float* __restrict__ ws_src,
    const float* __restrict__ ws_dst, u16* __restrict__ sig,
    const float* __restrict__ lin_W, u16* __restrict__ linwb,
    const float* __restrict__ W_ih0, u16* __restrict__ wx0) {
  if (blockIdx.x >= kG) {
    long cb = blockIdx.x - kG;                 // 0..1023
    long tid0 = cb * 256 + threadIdx.x;
    long stride = 1024L * 256;
    if (linwb) {
      long n8 = ((long)kVG * 1024) >> 3;
      for (long i = tid0; i < n8; i += stride) {
        long o = i * 8;
        short8 v = ld8bf(lin_W + o);
        *(short8*)(linwb + o) = v;
      }
    }
    const long n0w = 4096 * 640;
    for (long i = tid0; i < n0w; i += stride) {
      long row = i / 640, col = i - row * 640;
      wx0[i] = f2bf(col < 600 ? W_ih0[row * 600 + col] : 0.f);
    }
    return;
  }
  __shared__ float xs[32][301];
  __shared__ float a_s[32][4];
  __shared__ float a_d0[4];
  __shared__ float alpha[4][32];
  __shared__ float xw[4][301];
  __shared__ int allowed[32];
  int g = blockIdx.x, tid = threadIdx.x;
  const int* idx = x_indices + g * 32;
  for (int i = tid; i < 32 * 300; i += 256) {
    int j = i / 300, d2 = i - j * 300;
    xs[j][d2] = X[(size_t)idx[j] * 300 + d2];
  }
  if (tid < 32) allowed[tid] = (tid == 0) ? 1 : 0;
  __syncthreads();
  if (tid < 128) {
    int j = tid >> 2, h = tid & 3;
    float s = 0.f;
    for (int d2 = 0; d2 < 300; ++d2) s += xs[j][d2] * ws_src[d2 * 4 + h];
    a_s[j][h] = s;
  } else if (tid < 132) {
    int h = tid - 128; float s = 0.f;
    for (int d2 = 0; d2 < 300; ++d2) s += xs[0][d2] * ws_dst[d2 * 4 + h];
    a_d0[h] = s;
  } else if (tid >= 192) {
    int e = tid - 192;
    int src = edge_index[g * 128 + e];
    int dst = edge_index[g * 128 + 64 + e];
    if (dst == 0) allowed[src] = 1;
  }
  __syncthreads();
  if (tid < 4) {
    int h = tid;
    float ev[32];
    float mx = -1e30f;
    #pragma unroll
    for (int j = 0; j < 32; ++j) {
      float v = a_d0[h] + a_s[j][h];
      v = (v > 0.f) ? v : 0.2f * v;
      v = allowed[j] ? v : -1e9f;
      ev[j] = v; mx = fmaxf(mx, v);
    }
    float ssum = 0.f;
    #pragma unroll
    for (int j = 0; j < 32; ++j) { float p = fexp(ev[j] - mx); ev[j] = p; ssum += p; }
    float inv = 1.f / ssum;
    #pragma unroll
    for (int j = 0; j < 32; ++j) alpha[h][j] = ev[j] * inv;
  }
  __syncthreads();
  for (int i = tid; i < 4 * 300; i += 256) {
    int h = i / 300, d2 = i - h * 300;
    float s = 0.f;
    #pragma unroll
    for (int j = 0; j < 32; ++j) s += alpha[h][j] * xs[j][d2];
    xw[h][d2] = s;
  }
  __syncthreads();
  int t = g % 35, b = g / 35;
  u16* srow = sig + ((size_t)t * 32 + b) * 640;
  for (int hc = tid; hc < 300; hc += 256) {
    srow[hc] = f2bf(xs[0][hc]);           // curr_emb = X[idx 0]
    int h = hc / 75;
    float s = gat_bias[hc];
    for (int d2 = 0; d2 < 300; ++d2) s += xw[h][d2] * gat_W[d2 * 300 + hc];
    srow[300 + hc] = f2bf(s);
  }
  for (int i2 = 600 + tid; i2 < 640; i2 += 256) srow[i2] = 0;  // zero pad
}

// ---------------- bulk input-gate GEMM (gll16 dbuf + swizzled LDS) ----------
// gates written INTERLEAVED: gates[m][u*4+g]  (one float4 per (m,unit))
__global__ void __launch_bounds__(256, 4) gemm_ig(
    const u16* __restrict__ A, const u16* __restrict__ Bw,
    float* __restrict__ gates, int K) {
  int bid = blockIdx.x;
  int bm = bid % 9, bn = bid / 9;
  int m0 = bm * 128, n0 = bn * 128;
  int tid = threadIdx.x, w = tid >> 6, lane = tid & 63, l15 = lane & 15, lhi = lane >> 4;
  int wm = w & 1, wn = w >> 1;
  __shared__ u16 As[2][128][32];
  __shared__ u16 Bs[2][128][32];
  int cl = ((lane & 3) ^ ((lane >> 3) & 3)) * 8;
  int am0 = m0 + w * 32 + (lane >> 2);
  int am1 = am0 + 16;
  const u16* arow0 = A + (size_t)((am0 < kM) ? am0 : 0) * K + cl;
  const u16* arow1 = A + (size_t)((am1 < kM) ? am1 : 0) * K + cl;
  int bn0r = n0 + w * 32 + (lane >> 2);
  const u16* brow0 = Bw + (size_t)bn0r * K + cl;
  const u16* brow1 = Bw + (size_t)(bn0r + 16) * K + cl;
  const int koff = (lhi ^ ((l15 >> 1) & 3)) * 8;  // read-side swizzle

  f32x4 acc[4][4];
  #pragma unroll
  for (int i = 0; i < 4; ++i)
    #pragma unroll
    for (int j = 0; j < 4; ++j) { f32x4 z = {0.f, 0.f, 0.f, 0.f}; acc[i][j] = z; }

  auto ISSUE = [&](int k0, int buf) {
    gll16(arow0 + k0, &As[buf][w * 32][0]);
    gll16(arow1 + k0, &As[buf][w * 32 + 16][0]);
    gll16(brow0 + k0, &Bs[buf][w * 32][0]);
    gll16(brow1 + k0, &Bs[buf][w * 32 + 16][0]);
  };
  int nkt = K >> 5;
  ISSUE(0, 0);
  for (int kt = 0; kt < nkt; ++kt) {
    int cur = kt & 1;
    if (kt < nkt - 1) {
      ISSUE((kt + 1) * 32, cur ^ 1);
      asm volatile("s_waitcnt vmcnt(4)" ::: "memory");
    } else {
      asm volatile("s_waitcnt vmcnt(0)" ::: "memory");
    }
    __builtin_amdgcn_s_barrier();
    __builtin_amdgcn_sched_barrier(0);
    short8 bfr[4];
    #pragma unroll
    for (int nt = 0; nt < 4; ++nt)
      bfr[nt] = *(const short8*)&Bs[cur][wn * 64 + nt * 16 + l15][koff];
    #pragma unroll
    for (int mt = 0; mt < 4; ++mt) {
      short8 af = *(const short8*)&As[cur][wm * 64 + mt * 16 + l15][koff];
      #pragma unroll
      for (int nt = 0; nt < 4; ++nt)
        acc[mt][nt] = mfma16(af, bfr[nt], acc[mt][nt]);
    }
    __builtin_amdgcn_sched_barrier(0);
    __builtin_amdgcn_s_barrier();
  }
  #pragma unroll
  for (int mt = 0; mt < 4; ++mt) {
    #pragma unroll
    for (int r = 0; r < 4; ++r) {
      int m = m0 + wm * 64 + mt * 16 + lhi * 4 + r;
      if (m < kM) {
        float* orow = gates + (size_t)m * 4096;
        #pragma unroll
        for (int nt = 0; nt < 4; ++nt) {
          int n = n0 + wn * 64 + nt * 16 + l15;
          orow[(n & 1023) * 4 + (n >> 10)] = acc[mt][nt][r];
        }
      }
    }
  }
}

// ---------------- fused 3-layer LSTM wavefront, 128 blocks x 8 units --------
// 128 blocks x 512 threads (8 waves). Block p owns units [8p,8p+8) for all
// layers. Jobs (wave pairs, K-halves 512, 32 weight rows each):
//   w0-1: Whh0 x h0[s-1]                    -> pred0
//   w2-3: Wih1 x h0[s-1]                    -> pred1 (x-part)
//   w4-5: Whh1 x h1[s-2] -> pred1 (h-part); Wih2(LDS) x h1[s-2] -> pred2 (x)
//   w6-7: Whh2 x h2[s-3]                    -> pred2 (h-part)
// Each wave polls only 64 producer flags (its K-half).
__global__ void __launch_bounds__(512, 1) lstm_fused012(
    const float* __restrict__ W_hh,      // [3][4096][1024]
    const float* __restrict__ W_ih_rest, // [2][4096][1024]
    const float* __restrict__ gates,     // [1120][1024][4] f32 (layer0 x-part)
    const float* __restrict__ bias_sum,  // [3][4096]
    u16* __restrict__ hist0, u16* __restrict__ hist1, u16* __restrict__ hist2,
    unsigned* __restrict__ flags) {
  const int p = blockIdx.x;            // 0..127
  const int u0 = p * 8;
  const int tid = threadIdx.x;
  const int w = tid >> 6, lane = tid & 63, l15 = lane & 15, lhi = lane >> 4;
  const int khalf = w & 1;
  const int job = w >> 1;              // 0:L0H 1:L1X 2:L1H+L2X 3:L2H
  const int kbase = khalf * 512;
  __shared__ float pred0[2][32][33];
  __shared__ float pred1[4][32][33];
  __shared__ float pred2[4][32][33];
  __shared__ u16 wih2[32][1032];       // Wih2 rows (row = gate*8 + unit)

  // cooperative: Wih2 -> LDS (fp32 -> bf16)
  for (int i = tid; i < 32 * 128; i += 512) {
    int row = i >> 7;
    int k8 = (i & 127) * 8;
    size_t gr = (size_t)((row >> 3) * 1024 + u0 + (row & 7));
    short8 v = ld8bf(W_ih_rest + (size_t)4096 * 1024 + gr * 1024 + k8);
    *(short8*)&wih2[row][k8] = v;
  }

  // per-wave weight fragments: 2 fragment-groups x 16 kk = 128 VGPR
  const float* m1;
  if (job == 0)      m1 = W_hh;
  else if (job == 1) m1 = W_ih_rest;
  else if (job == 2) m1 = W_hh + (size_t)4096 * 1024;
  else               m1 = W_hh + (size_t)2 * 4096 * 1024;
  short8 rA[2][16];
  #pragma unroll
  for (int fg = 0; fg < 2; ++fg) {
    size_t gr = (size_t)((fg * 2 + (l15 >> 3)) * 1024 + u0 + (l15 & 7));
    const float* src = m1 + gr * 1024 + kbase + lhi * 8;
    #pragma unroll
    for (int kk = 0; kk < 16; ++kk) rA[fg][kk] = ld8bf(src + kk * 32);
  }

  // pointwise roles: task A = all 512 (layer tid>>8), task B = tid<256 (layer2)
  const int layerA = tid >> 8;
  const int pb = (tid & 255) >> 3, pj = tid & 7;
  float biasA[4], biasB[4];
  #pragma unroll
  for (int g = 0; g < 4; ++g) {
    biasA[g] = bias_sum[layerA * 4096 + g * 1024 + u0 + pj];
    biasB[g] = bias_sum[2 * 4096 + g * 1024 + u0 + pj];
  }
  float cA = 0.f, cB = 0.f;
  const unsigned* fp = flags + khalf * 64 + lane;   // 64 producers of K-half
  __syncthreads();

  for (int s = 0; s < 37; ++s) {
    bool active; const u16* hsrc;
    if (job == 0)      { active = (s >= 1 && s < 35);  hsrc = hist0 + (size_t)(s - 1) * 32768; }
    else if (job == 1) { active = (s >= 1 && s <= 35); hsrc = hist0 + (size_t)(s - 1) * 32768; }
    else if (job == 2) { active = (s >= 2 && s <= 36); hsrc = hist1 + (size_t)(s - 2) * 32768; }
    else               { active = (s >= 3 && s <= 36); hsrc = hist2 + (size_t)(s - 3) * 32768; }
    if (active) {
      unsigned tgt = (unsigned)s;
      while (!__all((int)(__hip_atomic_load(fp, __ATOMIC_RELAXED,
                                            __HIP_MEMORY_SCOPE_AGENT) >= tgt)))
        __builtin_amdgcn_s_sleep(1);
      asm volatile("" ::: "memory");   // pin h loads behind the wait
    }
    f32x4 a00 = {0,0,0,0}, a01 = {0,0,0,0}, a10 = {0,0,0,0}, a11 = {0,0,0,0};
    f32x4 x00 = {0,0,0,0}, x01 = {0,0,0,0}, x10 = {0,0,0,0}, x11 = {0,0,0,0};
    if (active) {
      const u16* b0p = hsrc + l15 * 1024 + kbase + lhi * 8;
      const u16* b1p = hsrc + (l15 + 16) * 1024 + kbase + lhi * 8;
      if (job == 2) {
        const int wrow0 = (l15 >> 3) * 8 + (l15 & 7);        // fg 0
        const int wrow1 = (2 + (l15 >> 3)) * 8 + (l15 & 7);  // fg 1
        #pragma unroll
        for (int kk = 0; kk < 16; ++kk) {
          short8 b0 = *(const short8*)(b0p + kk * 32);
          short8 b1 = *(const short8*)(b1p + kk * 32);
          a00 = mfma16(rA[0][kk], b0, a00);
          a01 = mfma16(rA[0][kk], b1, a01);
          a10 = mfma16(rA[1][kk], b0, a10);
          a11 = mfma16(rA[1][kk], b1, a11);
          short8 w0f = *(const short8*)&wih2[wrow0][kbase + kk * 32 + lhi * 8];
          short8 w1f = *(const short8*)&wih2[wrow1][kbase + kk * 32 + lhi * 8];
          x00 = mfma16(w0f, b0, x00);
          x01 = mfma16(w0f, b1, x01);
          x10 = mfma16(w1f, b0, x10);
          x11 = mfma16(w1f, b1, x11);
        }
      } else {
        #pragma unroll
        for (int kk = 0; kk < 16; ++kk) {
          short8 b0 = *(const short8*)(b0p + kk * 32);
          short8 b1 = *(const short8*)(b1p + kk * 32);
          a00 = mfma16(rA[0][kk], b0, a00);
          a01 = mfma16(rA[0][kk], b1, a01);
          a10 = mfma16(rA[1][kk], b0, a10);
          a11 = mfma16(rA[1][kk], b1, a11);
        }
      }
    }
    #pragma unroll
    for (int r = 0; r < 4; ++r) {
      int r0 = lhi * 4 + r, r1 = 16 + lhi * 4 + r;
      if (job == 0) {
        pred0[khalf][r0][l15] = a00[r];      pred0[khalf][r0][l15 + 16] = a01[r];
        pred0[khalf][r1][l15] = a10[r];      pred0[khalf][r1][l15 + 16] = a11[r];
      } else if (job == 1) {
        pred1[khalf][r0][l15] = a00[r];      pred1[khalf][r0][l15 + 16] = a01[r];
        pred1[khalf][r1][l15] = a10[r];      pred1[khalf][r1][l15 + 16] = a11[r];
      } else if (job == 2) {
        pred1[2 + khalf][r0][l15] = a00[r];  pred1[2 + khalf][r0][l15 + 16] = a01[r];
        pred1[2 + khalf][r1][l15] = a10[r];  pred1[2 + khalf][r1][l15 + 16] = a11[r];
        pred2[khalf][r0][l15] = x00[r];      pred2[khalf][r0][l15 + 16] = x01[r];
        pred2[khalf][r1][l15] = x10[r];      pred2[khalf][r1][l15 + 16] = x11[r];
      } else {
        pred2[2 + khalf][r0][l15] = a00[r];  pred2[2 + khalf][r0][l15 + 16] = a01[r];
        pred2[2 + khalf][r1][l15] = a10[r];  pred2[2 + khalf][r1][l15 + 16] = a11[r];
      }
    }
    __syncthreads();
    // task A: layer0 (t=s) or layer1 (t=s-1)
    bool actA = (layerA == 0) ? (s < 35) : (s >= 1 && s <= 35);
    if (actA) {
      float pre[4];
      if (layerA == 0) {
        #pragma unroll
        for (int g = 0; g < 4; ++g) {
          int row = g * 8 + pj;
          pre[g] = pred0[0][row][pb] + pred0[1][row][pb];
        }
        float4 gx = ((const float4*)gates)[(size_t)(s * 32 + pb) * 1024 + u0 + pj];
        pre[0] += gx.x; pre[1] += gx.y; pre[2] += gx.z; pre[3] += gx.w;
      } else {
        #pragma unroll
        for (int g = 0; g < 4; ++g) {
          int row = g * 8 + pj;
          pre[g] = pred1[0][row][pb] + pred1[1][row][pb] +
                   pred1[2][row][pb] + pred1[3][row][pb];
        }
      }
      float iv = pre[0] + biasA[0];
      float fv = pre[1] + biasA[1];
      float gv = pre[2] + biasA[2];
      float ov = pre[3] + biasA[3];
      float cc = fsigm(fv) * cA + fsigm(iv) * ftanh(gv);
      float hh = fsigm(ov) * ftanh(cc);
      cA = cc;
      int t = s - layerA;
      u16* dst = (layerA == 0) ? hist0 : hist1;
      store_u16_llc(dst + ((size_t)(t * 32 + pb) << 10) + u0 + pj, f2bf(hh));
    }
    // task B: layer2 (t=s-2), threads < 256
    if (tid < 256 && s >= 2) {
      float pre[4];
      #pragma unroll
      for (int g = 0; g < 4; ++g) {
        int row = g * 8 + pj;
        pre[g] = pred2[0][row][pb] + pred2[1][row][pb] +
                 pred2[2][row][pb] + pred2[3][row][pb];
      }
      float iv = pre[0] + biasB[0];
      float fv = pre[1] + biasB[1];
      float gv = pre[2] + biasB[2];
      float ov = pre[3] + biasB[3];
      float cc = fsigm(fv) * cB + fsigm(iv) * ftanh(gv);
      float hh = fsigm(ov) * ftanh(cc);
      cB = cc;
      int t = s - 2;
      store_u16_llc(hist2 + ((size_t)(t * 32 + pb) << 10) + u0 + pj, f2bf(hh));
    }
    __syncthreads();   // drains LLC stores + pred reuse safety
    if (s < 36 && tid == 0)
      __hip_atomic_store(flags + p, (unsigned)(s + 1),
                         __ATOMIC_RELAXED, __HIP_MEMORY_SCOPE_AGENT);
  }
}

// ---------------- logits GEMM, 128x256 tile (gll16 dbuf + swizzled LDS) -----
__global__ void __launch_bounds__(256, 2) gemm_logits_async(
    const u16* __restrict__ hist2, const u16* __restrict__ linwb,
    const float* __restrict__ lin_b, float* __restrict__ out,
    float2* __restrict__ partials) {
  int nwg = gridDim.x, orig = blockIdx.x;
  int q = nwg >> 3, r = nwg & 7, xcd = orig & 7, off = orig >> 3;
  int bid = (xcd < r ? xcd * (q + 1) : r * (q + 1) + (xcd - r) * q) + off;
  int bm = bid % 9, bn = bid / 9;
  int m0 = bm * 128, n0 = bn * 256;
  int tid = threadIdx.x, w = tid >> 6, lane = tid & 63, l15 = lane & 15, lhi = lane >> 4;
  int wm = w & 1, wn = w >> 1;
  __shared__ u16 As[2][128][32];
  __shared__ u16 Bs[2][256][32];
  int cl = ((lane & 3) ^ ((lane >> 3) & 3)) * 8;
  int am0 = m0 + w * 32 + (lane >> 2);
  int am1 = am0 + 16;
  int mm0 = (am0 < kM) ? am0 : 0, mm1 = (am1 < kM) ? am1 : 0;
  const u16* arow0 = hist2 + (((size_t)((mm0 % 35) * 32 + mm0 / 35)) << 10) + cl;
  const u16* arow1 = hist2 + (((size_t)((mm1 % 35) * 32 + mm1 / 35)) << 10) + cl;
  const u16* browq[4];
  #pragma unroll
  for (int q2 = 0; q2 < 4; ++q2) {
    int nr = n0 + w * 64 + q2 * 16 + (lane >> 2);
    int nn = (nr < kVG) ? nr : 0;
    browq[q2] = linwb + ((size_t)nn << 10) + cl;
  }
  const int koff = (lhi ^ ((l15 >> 1) & 3)) * 8;

  f32x4 acc[4][8];
  #pragma unroll
  for (int i = 0; i < 4; ++i)
    #pragma unroll
    for (int j = 0; j < 8; ++j) { f32x4 z = {0.f, 0.f, 0.f, 0.f}; acc[i][j] = z; }

  auto ISSUE = [&](int k0, int buf) {
    gll16(arow0 + k0, &As[buf][w * 32][0]);
    gll16(arow1 + k0, &As[buf][w * 32 + 16][0]);
    #pragma unroll
    for (int q2 = 0; q2 < 4; ++q2)
      gll16(browq[q2] + k0, &Bs[buf][w * 64 + q2 * 16][0]);
  };
  ISSUE(0, 0);
  for (int kt = 0; kt < 32; ++kt) {
    int cur = kt & 1;
    if (kt < 31) {
      ISSUE((kt + 1) * 32, cur ^ 1);
      asm volatile("s_waitcnt vmcnt(6)" ::: "memory");
    } else {
      asm volatile("s_waitcnt vmcnt(0)" ::: "memory");
    }
    __builtin_amdgcn_s_barrier();
    __builtin_amdgcn_sched_barrier(0);
    short8 bfr[8];
    #pragma unroll
    for (int nt = 0; nt < 8; ++nt)
      bfr[nt] = *(const short8*)&Bs[cur][wn * 128 + nt * 16 + l15][koff];
    #pragma unroll
    for (int mt = 0; mt < 4; ++mt) {
      short8 af = *(const short8*)&As[cur][wm * 64 + mt * 16 + l15][koff];
      #pragma unroll
      for (int nt = 0; nt < 8; ++nt)
        acc[mt][nt] = mfma16(af, bfr[nt], acc[mt][nt]);
    }
    __builtin_amdgcn_sched_barrier(0);
    __builtin_amdgcn_s_barrier();
  }
  float bcol[8]; int ncol[8];
  #pragma unroll
  for (int nt = 0; nt < 8; ++nt) {
    int n = n0 + wn * 128 + nt * 16 + l15;
    ncol[nt] = n;
    bcol[nt] = (n < kVG) ? lin_b[n] : -INFINITY;
  }
  #pragma unroll
  for (int mt = 0; mt < 4; ++mt) {
    #pragma unroll
    for (int r = 0; r < 4; ++r) {
      int m = m0 + wm * 64 + mt * 16 + lhi * 4 + r;
      bool mok = (m < kM);
      float v[8];
      #pragma unroll
      for (int nt = 0; nt < 8; ++nt) v[nt] = acc[mt][nt][r] + bcol[nt];
      if (mok) {
        float* orow = out + (size_t)m * kVG;
        #pragma unroll
        for (int nt = 0; nt < 8; ++nt)
          if (ncol[nt] < kVG) orow[ncol[nt]] = v[nt];
      }
      #pragma unroll
      for (int half = 0; half < 2; ++half) {
        float v0 = v[half * 4], v1 = v[half * 4 + 1];
        float v2 = v[half * 4 + 2], v3 = v[half * 4 + 3];
        float mx = fmaxf(fmaxf(v0, v1), fmaxf(v2, v3));
        #pragma unroll
        for (int d2 = 1; d2 < 16; d2 <<= 1) mx = fmaxf(mx, __shfl_xor(mx, d2, 64));
        float sv = 0.f;
        sv += (v0 > -1e30f) ? fexp(v0 - mx) : 0.f;
        sv += (v1 > -1e30f) ? fexp(v1 - mx) : 0.f;
        sv += (v2 > -1e30f) ? fexp(v2 - mx) : 0.f;
        sv += (v3 > -1e30f) ? fexp(v3 - mx) : 0.f;
        #pragma unroll
        for (int d2 = 1; d2 < 16; d2 <<= 1) sv += __shfl_xor(sv, d2, 64);
        if (mok && l15 == 0)
          partials[(size_t)m * 784 + bn * 4 + wn * 2 + half] = make_float2(mx, sv);
      }
    }
  }
}

// fallback (no bf16 workspace image): reg-staged, fp32 B inline-converted
__global__ void __launch_bounds__(256, 1) gemm_logits_fb(
    const u16* __restrict__ hist2, const float* __restrict__ lin_W,
    const float* __restrict__ lin_b, float* __restrict__ out,
    float2* __restrict__ partials) {
  int nwg = gridDim.x, orig = blockIdx.x;
  int q = nwg >> 3, r = nwg & 7, xcd = orig & 7, off = orig >> 3;
  int bid = (xcd < r ? xcd * (q + 1) : r * (q + 1) + (xcd - r) * q) + off;
  int bm = bid % 9, bn = bid / 9;
  int m0 = bm * 128, n0 = bn * 128;
  int tid = threadIdx.x, w = tid >> 6, lane = tid & 63, l15 = lane & 15, lhi = lane >> 4;
  int wm = w & 1, wn = w >> 1;
  __shared__ u16 As[128][40];
  __shared__ u16 Bs[128][40];
  f32x4 acc[4][4];
  #pragma unroll
  for (int i = 0; i < 4; ++i)
    #pragma unroll
    for (int j = 0; j < 4; ++j) { f32x4 z = {0.f, 0.f, 0.f, 0.f}; acc[i][j] = z; }
  for (int kt = 0; kt < 32; ++kt) {
    int k0 = kt * 32;
    #pragma unroll
    for (int q2 = 0; q2 < 2; ++q2) {
      int c = tid * 2 + q2; int row = c >> 2; int ch = c & 3;
      int m = m0 + row;
      uint4 av{0u, 0u, 0u, 0u};
      if (m < kM) {
        int b = m / 35; int t = m - b * 35;
        av = *(const uint4*)(hist2 + ((size_t)(t * 32 + b) << 10) + k0 + ch * 8);
      }
      *(uint4*)&As[row][ch * 8] = av;
      int n = n0 + row;
      uint4 bv{0u, 0u, 0u, 0u};
      if (n < kVG) {
        const float* src = lin_W + (size_t)n * 1024 + k0 + ch * 8;
        float4 f0 = *(const float4*)(src);
        float4 f1 = *(const float4*)(src + 4);
        bv.x = (unsigned)f2bf(f0.x) | ((unsigned)f2bf(f0.y) << 16);
        bv.y = (unsigned)f2bf(f0.z) | ((unsigned)f2bf(f0.w) << 16);
        bv.z = (unsigned)f2bf(f1.x) | ((unsigned)f2bf(f1.y) << 16);
        bv.w = (unsigned)f2bf(f1.z) | ((unsigned)f2bf(f1.w) << 16);
      }
      *(uint4*)&Bs[row][ch * 8] = bv;
    }
    __syncthreads();
    short8 bfr[4];
    #pragma unroll
    for (int nt = 0; nt < 4; ++nt)
      bfr[nt] = *(const short8*)&Bs[wn * 64 + nt * 16 + l15][lhi * 8];
    #pragma unroll
    for (int mt = 0; mt < 4; ++mt) {
      short8 af = *(const short8*)&As[wm * 64 + mt * 16 + l15][lhi * 8];
      #pragma unroll
      for (int nt = 0; nt < 4; ++nt)
        acc[mt][nt] = mfma16(af, bfr[nt], acc[mt][nt]);
    }
    __syncthreads();
  }
  float bcol[4]; int ncol[4];
  #pragma unroll
  for (int nt = 0; nt < 4; ++nt) {
    int n = n0 + wn * 64 + nt * 16 + l15;
    ncol[nt] = n;
    bcol[nt] = (n < kVG) ? lin_b[n] : -INFINITY;
  }
  #pragma unroll
  for (int mt = 0; mt < 4; ++mt) {
    #pragma unroll
    for (int r = 0; r < 4; ++r) {
      int m = m0 + wm * 64 + mt * 16 + lhi * 4 + r;
      float v0 = acc[mt][0][r] + bcol[0];
      float v1 = acc[mt][1][r] + bcol[1];
      float v2 = acc[mt][2][r] + bcol[2];
      float v3 = acc[mt][3][r] + bcol[3];
      bool mok = (m < kM);
      if (mok) {
        float* orow = out + (size_t)m * kVG;
        if (ncol[0] < kVG) orow[ncol[0]] = v0;
        if (ncol[1] < kVG) orow[ncol[1]] = v1;
        if (ncol[2] < kVG) orow[ncol[2]] = v2;
        if (ncol[3] < kVG) orow[ncol[3]] = v3;
      }
      float mx = fmaxf(fmaxf(v0, v1), fmaxf(v2, v3));
      #pragma unroll
      for (int d2 = 1; d2 < 16; d2 <<= 1) mx = fmaxf(mx, __shfl_xor(mx, d2, 64));
      float sv = 0.f;
      sv += (v0 > -1e30f) ? fexp(v0 - mx) : 0.f;
      sv += (v1 > -1e30f) ? fexp(v1 - mx) : 0.f;
      sv += (v2 > -1e30f) ? fexp(v2 - mx) : 0.f;
      sv += (v3 > -1e30f) ? fexp(v3 - mx) : 0.f;
      #pragma unroll
      for (int d2 = 1; d2 < 16; d2 <<= 1) sv += __shfl_xor(sv, d2, 64);
      if (mok && l15 == 0)
        partials[(size_t)m * 784 + bn * 2 + wn] = make_float2(mx, sv);
    }
  }
}

// ---------------- row logsumexp reduce --------------------------------------
__global__ void reduce_rows(const float2* __restrict__ partials, float* __restrict__ lse) {
  int m = blockIdx.x, tid = threadIdx.x;
  float mx = -INFINITY, s = 0.f;
  for (int j = tid; j < 782; j += 256) {
    float2 p = partials[(size_t)m * 784 + j];
    if (p.x > mx) { s = s * fexp(mx - p.x) + p.y; mx = p.x; }
    else          { s += p.y * fexp(p.x - mx); }
  }
  for (int d = 1; d < 64; d <<= 1) {
    float omx = __shfl_xor(mx, d, 64);
    float os  = __shfl_xor(s, d, 64);
    if (omx > mx) { s = s * fexp(mx - omx) + os; mx = omx; }
    else          { s += os * fexp(omx - mx); }
  }
  __shared__ float smx[4], ssum[4];
  int w = tid >> 6;
  if ((tid & 63) == 0) { smx[w] = mx; ssum[w] = s; }
  __syncthreads();
  if (tid == 0) {
    for (int i = 1; i < 4; ++i) {
      float omx = smx[i], os = ssum[i];
      if (omx > mx) { s = s * fexp(mx - omx) + os; mx = omx; }
      else          { s += os * fexp(omx - mx); }
    }
    lse[m] = mx + logf(s);
  }
}

// ---------------- in-place log_softmax subtract -----------------------------
__global__ void sub_lse(float* __restrict__ out, const float* __restrict__ lse) {
  const int total4 = 14000000;  // 1120*50000/4
  for (int i = blockIdx.x * blockDim.x + threadIdx.x; i < total4; i += gridDim.x * blockDim.x) {
    int m = i / 12500;
    float4 v = ((float4*)out)[i];
    float L = lse[m];
    v.x -= L; v.y -= L; v.z -= L; v.w -= L;
    ((float4*)out)[i] = v;
  }
}

// ---------------- launch ----------------------------------------------------
extern "C" void kernel_launch(void* const* d_in, const int* in_sizes, int n_in,
                              void* d_out, int out_size, void* d_ws, size_t ws_size,
                              hipStream_t stream) {
  const int*   x_indices  = (const int*)d_in[0];
  const int*   edge_index = (const int*)d_in[1];
  const float* X          = (const float*)d_in[2];
  const float* gat_W      = (const float*)d_in[3];
  const float* att_src    = (const float*)d_in[4];
  const float* att_dst    = (const float*)d_in[5];
  const float* gat_bias   = (const float*)d_in[6];
  const float* W_ih0      = (const float*)d_in[7];
  const float* W_ih_rest  = (const float*)d_in[8];
  const float* W_hh       = (const float*)d_in[9];
  const float* b_ih       = (const float*)d_in[10];
  const float* b_hh       = (const float*)d_in[11];
  const float* lin_W      = (const float*)d_in[12];
  const float* lin_b      = (const float*)d_in[13];
  float* out = (float*)d_out;
  char* ws = (char*)d_ws;

  unsigned* flags    = (unsigned*)(ws + OFF_BAR);
  float*    ws_src   = (float*)(ws + OFF_WSRC);
  float*    ws_dst   = (float*)(ws + OFF_WDST);
  float*    bias_sum = (float*)(ws + OFF_BIAS);
  u16*      sig      = (u16*)(ws + OFF_SIG);
  u16*      wx0      = (u16*)(ws + OFF_WX0);
  float*    gates    = (float*)(ws + OFF_GATES);
  u16*      hist     = (u16*)(ws + OFF_HIST);
  float2*   partials = (float2*)(ws + OFF_PART);
  float*    lse      = (float*)(ws + OFF_LSE);
  u16*      linwb    = (u16*)(ws + OFF_LINWB);
  bool use_bw = (ws_size >= kNeedBW);

  u16* hist0 = hist;
  u16* hist1 = hist + (size_t)35 * 32 * 1024;
  u16* hist2 = hist + (size_t)2 * 35 * 32 * 1024;

  hipMemsetAsync(ws + OFF_BAR, 0, 1024, stream);
  prep_small<<<64, 256, 0, stream>>>(gat_W, att_src, att_dst, b_ih, b_hh,
                                     ws_src, ws_dst, bias_sum);
  // GAT + weight conversions fused (role-split grid)
  gat_conv<<<kG + 1024, 256, 0, stream>>>(
      x_indices, edge_index, X, gat_W, gat_bias, ws_src, ws_dst, sig,
      lin_W, use_bw ? linwb : nullptr, W_ih0, wx0);
  // layer 0 input transform (bulk)
  gemm_ig<<<288, 256, 0, stream>>>(sig, wx0, gates, 640);
  // fused 3-layer wavefront (37 supersteps, 128 blocks, dataflow flags)
  lstm_fused012<<<128, 512, 0, stream>>>(W_hh, W_ih_rest, gates, bias_sum,
                                         hist0, hist1, hist2, flags);
  // logits + log_softmax
  if (use_bw)
    gemm_logits_async<<<9 * 196, 256, 0, stream>>>(hist2, linwb, lin_b, out, partials);
  else
    gemm_logits_fb<<<9 * 391, 256, 0, stream>>>(hist2, lin_W, lin_b, out, partials);
  reduce_rows<<<kG, 256, 0, stream>>>(partials, lse);
  sub_lse<<<2048, 256, 0, stream>>>(out, lse);
}